// Round 4
// baseline (261.163 us; speedup 1.0000x reference)
//
#include <hip/hip_runtime.h>
#include <hip/hip_bf16.h>

// GCNConv encoder — R18: single-pass degree counting, minimal bucketed traffic.
//   passA:  multisplit scatter + INLINE global atomicAdd degree count (fire-and-forget)
//   b1scale: pure streaming h *= rsqrt(cnt+1), uint4-vectorized (no bucketed read)
//   B2:     degrees read from cnt[] (512B) -> wave shfl-scan (no block-wide scan barriers),
//           ONE bucketed read (sort scatter), register sweep w/ MLP-16 gathers,
//           ds_add_f32 segment flush, epilogue rsqrt from LDS cnt (no dinv array).
//   gemm:   64-row tile [unchanged]
// LESSON (R15/R16, 433us): per-edge ordered LDS ops in the gather loop defeat load
// batching. Register-accumulate, flush rarely (R17: 50us).
//
// ws: dinv[n] f32 (fallback only) | h[n*32] bf16 | bucketed[NB*CAP] u32 | [bcursor 1024 | cnt n] i32

#define LATD 32
#define INCH 128
#define BSH 7
#define BW 128
#define CAP 4096
#define ACH 2048

__device__ __forceinline__ void lds_fadd(float* p, float v) {
    // generic pointer to __shared__ carries the 32-bit LDS byte offset in its low word
    unsigned off = (unsigned)(unsigned long long)p;
    asm volatile("ds_add_f32 %0, %1" :: "v"(off), "v"(v) : "memory");
}

__device__ __forceinline__ void load_edge(const int* __restrict__ ei, const int* __restrict__ yei,
                                          int e1, int e2, int e, int& src, int& dst) {
    if (e < e1) { src = ei[e]; dst = ei[e1 + e]; }
    else        { int t = e - e1; src = yei[t]; dst = yei[e2 + t]; }
}

__device__ __forceinline__ unsigned bf2_scale(unsigned u, float dv) {
    __hip_bfloat162 v = *(__hip_bfloat162*)&u;
    float2 f = __bfloat1622float2(v);
    f.x *= dv; f.y *= dv;
    __hip_bfloat162 r = __float22bfloat162_rn(f);
    return *(unsigned*)&r;
}

// ---------------- GEMM v3 (proven R14): 64-row tile, bf16 x-staging, 256 thr ----------------
__global__ __launch_bounds__(256) void gemm_tile_k(const float* __restrict__ x,
                                                   const float* __restrict__ W,
                                                   __hip_bfloat16* __restrict__ h, int n) {
    __shared__ __hip_bfloat16 xs[64][136];
    __shared__ float Wl[INCH][LATD];
    int tid = threadIdx.x;
    {
        const float4* Wv = (const float4*)W;
        float4* Wlv = (float4*)&Wl[0][0];
#pragma unroll 2
        for (int i = 0; i < 4; ++i) Wlv[tid + 256 * i] = Wv[tid + 256 * i];
    }
    int row0 = blockIdx.x * 64;
#pragma unroll 4
    for (int v = tid; v < 64 * 32; v += 256) {
        int r = v >> 5, kc = v & 31;
        int gr = row0 + r;
        float4 val = make_float4(0.f, 0.f, 0.f, 0.f);
        if (gr < n) val = ((const float4*)(x + (size_t)gr * INCH))[kc];
        __hip_bfloat16 t4[4] = { __float2bfloat16(val.x), __float2bfloat16(val.y),
                                 __float2bfloat16(val.z), __float2bfloat16(val.w) };
        *(ushort4*)&xs[r][kc * 4] = *(const ushort4*)t4;
    }
    __syncthreads();
    int c = tid & 7, rr = tid >> 3;
    int j0 = c * 4, r0 = rr * 2;
    float acc[2][4] = {};
#pragma unroll 2
    for (int kk = 0; kk < INCH; kk += 4) {
        float4 w0 = *(const float4*)&Wl[kk + 0][j0];
        float4 w1 = *(const float4*)&Wl[kk + 1][j0];
        float4 w2 = *(const float4*)&Wl[kk + 2][j0];
        float4 w3 = *(const float4*)&Wl[kk + 3][j0];
#pragma unroll
        for (int ri = 0; ri < 2; ++ri) {
            ushort4 u = *(const ushort4*)&xs[r0 + ri][kk];
            float a0 = __bfloat162float(*(const __hip_bfloat16*)&u.x);
            float a1 = __bfloat162float(*(const __hip_bfloat16*)&u.y);
            float a2 = __bfloat162float(*(const __hip_bfloat16*)&u.z);
            float a3 = __bfloat162float(*(const __hip_bfloat16*)&u.w);
            acc[ri][0] += a0 * w0.x + a1 * w1.x + a2 * w2.x + a3 * w3.x;
            acc[ri][1] += a0 * w0.y + a1 * w1.y + a2 * w2.y + a3 * w3.y;
            acc[ri][2] += a0 * w0.z + a1 * w1.z + a2 * w2.z + a3 * w3.z;
            acc[ri][3] += a0 * w0.w + a1 * w1.w + a2 * w2.w + a3 * w3.w;
        }
    }
#pragma unroll
    for (int ri = 0; ri < 2; ++ri) {
        int gr = row0 + r0 + ri;
        if (gr < n) {
            __hip_bfloat16 tmp[4];
#pragma unroll
            for (int cj = 0; cj < 4; ++cj) tmp[cj] = __float2bfloat16(acc[ri][cj]);
            *(ushort4*)(&h[(size_t)gr * LATD + j0]) = *(const ushort4*)tmp;
        }
    }
}

__global__ void zero_i32_k(int* p, int cnt) {
    int i = blockIdx.x * 256 + threadIdx.x;
    if (i < cnt) p[i] = 0;
}

// ---------------- pass A: multisplit + inline global degree count ----------------
__global__ __launch_bounds__(512) void passA_scatter_k(const int* __restrict__ ei, const int* __restrict__ yei,
                                                       int e1, int e2, int* __restrict__ bcursor,
                                                       unsigned* __restrict__ bucketed,
                                                       int* __restrict__ cntg, int NB) {
    __shared__ int hist[1024];
    __shared__ int scanex[1024];
    __shared__ int segb[1024];
    __shared__ int sd[512];
    __shared__ unsigned raw[ACH];           // pk in arrival order
    __shared__ unsigned short rawb[ACH];    // bucket in arrival order
    __shared__ unsigned stage[ACH];         // pk sorted by bucket
    __shared__ unsigned short bof[ACH];     // bucket sorted
    int tid = threadIdx.x;
    int E = e1 + e2;
    int e0 = blockIdx.x * ACH;
    int m = E - e0; if (m > ACH) m = ACH;
    for (int i = tid; i < 1024; i += 512) hist[i] = 0;
    __syncthreads();
    for (int i = tid; i < m; i += 512) {
        int src, dst; load_edge(ei, yei, e1, e2, e0 + i, src, dst);
        int b = dst >> BSH;
        raw[i]  = ((unsigned)src << BSH) | (unsigned)(dst & (BW - 1));
        rawb[i] = (unsigned short)b;
        atomicAdd(&hist[b], 1);
        atomicAdd(&cntg[dst], 1);           // global degree count, fire-and-forget
    }
    __syncthreads();
    int b2 = tid * 2;
    int c0 = hist[b2], c1 = hist[b2 + 1];
    int tot2 = c0 + c1;
    sd[tid] = tot2;
    __syncthreads();
    int val = tot2;
    for (int off = 1; off < 512; off <<= 1) {
        int t = (tid >= off) ? sd[tid - off] : 0;
        __syncthreads();
        val += t;
        sd[tid] = val;
        __syncthreads();
    }
    int eb = val - tot2;
    scanex[b2] = eb; scanex[b2 + 1] = eb + c0;
    __syncthreads();
    for (int b = tid; b < NB; b += 512)
        segb[b] = hist[b] ? atomicAdd(&bcursor[b], hist[b]) : 0;
    __syncthreads();
    for (int b = tid; b < 1024; b += 512) hist[b] = scanex[b];   // repurpose as cursor
    __syncthreads();
    for (int i = tid; i < m; i += 512) {
        unsigned pk = raw[i]; int b = rawb[i];
        int pos = atomicAdd(&hist[b], 1);
        stage[pos] = pk;
        bof[pos] = (unsigned short)b;
    }
    __syncthreads();
    for (int i = tid; i < m; i += 512) {
        int b = bof[i];
        int pos = segb[b] + (i - scanex[b]);
        if (pos < CAP)
            bucketed[(size_t)b * CAP + pos] = stage[i];
    }
}

// ---------------- b1scale: h *= rsqrt(cnt+1), uint4-vectorized streaming RMW ----------------
__global__ __launch_bounds__(256) void b1scale_k(const int* __restrict__ cnt,
                                                 unsigned* __restrict__ h2, int n) {
    int idx = blockIdx.x * 256 + threadIdx.x;      // one uint4 (8 bf16) per thread
    int total = n * 4;
    if (idx >= total) return;
    int node = idx >> 2;
    float dv = rsqrtf((float)cnt[node] + 1.0f);
    uint4 u = ((uint4*)h2)[idx];
    u.x = bf2_scale(u.x, dv);
    u.y = bf2_scale(u.y, dv);
    u.z = bf2_scale(u.z, dv);
    u.w = bf2_scale(u.w, dv);
    ((uint4*)h2)[idx] = u;
}

// ---------------- B2: cnt from global; wave scan; one sort pass; register sweep ----------------
__global__ __launch_bounds__(512) void passB2_k(const unsigned* __restrict__ bucketed,
                                                const int* __restrict__ bcursor,
                                                const int* __restrict__ cntg,
                                                const __hip_bfloat16* __restrict__ hs,
                                                const float* __restrict__ bias,
                                                float* __restrict__ out, int n) {
    __shared__ unsigned sorted[CAP];     // 16 KB
    __shared__ float oacc[BW][LATD];     // 16 KB accumulator tile (this block owns dst rows)
    __shared__ int cnt[BW], cur[BW];
    int tid = threadIdx.x;
    int b = blockIdx.x;
    size_t s = (size_t)b * CAP;
    int tot = bcursor[b]; if (tot > CAP) tot = CAP;
    int dst0 = b << BSH;
    for (int i = tid; i < BW * LATD; i += 512) ((float*)oacc)[i] = 0.f;
    if (tid < BW) {
        int node = dst0 + tid;
        cnt[tid] = (node < n) ? cntg[node] : 0;
    }
    __syncthreads();
    // wave-0 exclusive scan over 128 counts (2 per lane), no block barriers inside
    if (tid < 64) {
        int b2 = tid * 2;
        int c0 = cnt[b2], c1 = cnt[b2 + 1];
        int pair = c0 + c1;
        int incl = pair;
#pragma unroll
        for (int off = 1; off < 64; off <<= 1) {
            int t = __shfl_up(incl, off);
            if (tid >= off) incl += t;
        }
        int excl = incl - pair;
        cur[b2] = excl; cur[b2 + 1] = excl + c0;
    }
    __syncthreads();
    // counting-sort scatter into LDS (the ONLY bucketed read in B2)
    for (int i = tid; i < tot; i += 512) {
        unsigned e = bucketed[s + i];
        int p = atomicAdd(&cur[e & (BW - 1)], 1);
        if (p < CAP) sorted[p] = e;
    }
    __syncthreads();
    // segmented sweep: register accumulation, MLP-16 gather batches (NO memory ops
    // in the gather loop), rare ds_add_f32 flush per node-segment
    int g = tid >> 5, j = tid & 31;
    int span = (((tot + 15) >> 4) + 31) & ~31;
    int gs = g * span;
    int ge = gs + span; if (ge > tot) ge = tot;
    if (gs < tot) {
        float acc = 0.0f;
        int cur_ld = -1;
        for (int base = gs; base < ge; base += 32) {
            int mm = ge - base; if (mm > 32) mm = 32;
            if (mm == 32) {
#pragma unroll
                for (int ph = 0; ph < 2; ++ph) {
                    unsigned pk16[16]; float v16[16];
#pragma unroll
                    for (int t = 0; t < 16; ++t) {
                        pk16[t] = sorted[base + ph * 16 + t];              // LDS broadcast
                        v16[t] = __bfloat162float(hs[(size_t)(pk16[t] >> BSH) * LATD + j]);
                    }
#pragma unroll
                    for (int t = 0; t < 16; ++t) {
                        int ld = (int)(pk16[t] & (BW - 1));
                        if (ld != cur_ld) {
                            if (cur_ld >= 0) lds_fadd(&oacc[cur_ld][j], acc);
                            cur_ld = ld; acc = 0.0f;
                        }
                        acc += v16[t];
                    }
                }
            } else {
#pragma unroll 4
                for (int t = 0; t < mm; ++t) {
                    unsigned pk = sorted[base + t];
                    float v = __bfloat162float(hs[(size_t)(pk >> BSH) * LATD + j]);
                    int ld = (int)(pk & (BW - 1));
                    if (ld != cur_ld) {
                        if (cur_ld >= 0) lds_fadd(&oacc[cur_ld][j], acc);
                        cur_ld = ld; acc = 0.0f;
                    }
                    acc += v;
                }
            }
        }
        if (cur_ld >= 0) lds_fadd(&oacc[cur_ld][j], acc);
    }
    __syncthreads();   // waits lgkmcnt(0) -> all ds_add flushes visible
    // out = (neigh_acc + hs_self) * dinv + bias   (hs already = h * dinv; dinv from cnt)
    for (int idx = tid; idx < BW * (LATD / 4); idx += 512) {
        int ld = idx >> 3, q = idx & 7;
        int node = dst0 + ld;
        if (node >= n) continue;
        float dv = rsqrtf((float)cnt[ld] + 1.0f);
        int j0 = q * 4;
        ushort4 u = *(const ushort4*)&hs[(size_t)node * LATD + j0];
        float4 bv = *(const float4*)&bias[j0];
        float4 o;
        o.x = (oacc[ld][j0 + 0] + __bfloat162float(*(const __hip_bfloat16*)&u.x)) * dv + bv.x;
        o.y = (oacc[ld][j0 + 1] + __bfloat162float(*(const __hip_bfloat16*)&u.y)) * dv + bv.y;
        o.z = (oacc[ld][j0 + 2] + __bfloat162float(*(const __hip_bfloat16*)&u.z)) * dv + bv.z;
        o.w = (oacc[ld][j0 + 3] + __bfloat162float(*(const __hip_bfloat16*)&u.w)) * dv + bv.w;
        *(float4*)&out[(size_t)node * LATD + j0] = o;
    }
}

// ---------------- fallback path (atomic scatter; uses UNSCALED h) ----------------
__global__ void count_k(const int* __restrict__ ei, const int* __restrict__ yei,
                        int* __restrict__ cnt, int e1, int e2) {
    int e = blockIdx.x * 256 + threadIdx.x;
    if (e >= e1 + e2) return;
    int src, dst; load_edge(ei, yei, e1, e2, e, src, dst);
    atomicAdd(&cnt[dst], 1);
}

__global__ void dinv_k(const int* __restrict__ cnt, float* __restrict__ dinv, int n) {
    int i = blockIdx.x * 256 + threadIdx.x;
    if (i < n) dinv[i] = rsqrtf((float)cnt[i] + 1.0f);
}

__global__ void selfbias_k(const float* __restrict__ dinv, const __hip_bfloat16* __restrict__ h,
                           const float* __restrict__ b, float* __restrict__ out, int total) {
    int idx = blockIdx.x * 256 + threadIdx.x;
    if (idx >= total) return;
    int i = idx >> 5, j = idx & 31;
    float d = dinv[i];
    out[idx] = __bfloat162float(h[idx]) * d * d + b[j];
}

__global__ void scatter_atomic_k(const int* __restrict__ ei, const int* __restrict__ yei,
                                 const float* __restrict__ dinv, const __hip_bfloat16* __restrict__ h,
                                 float* __restrict__ out, int e1, int e2) {
    int idx = blockIdx.x * 256 + threadIdx.x;
    int e = idx >> 5;
    if (e >= e1 + e2) return;
    int j = idx & 31;
    int src, dst; load_edge(ei, yei, e1, e2, e, src, dst);
    float norm = dinv[src] * dinv[dst];
    atomicAdd(&out[(size_t)dst * LATD + j], __bfloat162float(h[(size_t)src * LATD + j]) * norm);
}

static inline size_t aln(size_t x) { return (x + 255) & ~(size_t)255; }

extern "C" void kernel_launch(void* const* d_in, const int* in_sizes, int n_in,
                              void* d_out, int out_size, void* d_ws, size_t ws_size,
                              hipStream_t stream) {
    const float* x  = (const float*)d_in[0];
    const int* ei   = (const int*)d_in[1];
    const int* yei  = (const int*)d_in[2];
    const float* W  = (const float*)d_in[3];
    const float* b  = (const float*)d_in[4];
    float* out = (float*)d_out;

    int n  = in_sizes[0] / INCH;
    int e1 = in_sizes[1] / 2;
    int e2 = in_sizes[2] / 2;
    int E  = e1 + e2;
    int NB = (n + BW - 1) >> BSH;

    char* p = (char*)d_ws;
    size_t off = 0;
    float* dinv = (float*)(p + off);            off += aln((size_t)n * 4);
    __hip_bfloat16* h = (__hip_bfloat16*)(p + off); off += aln((size_t)n * LATD * 2);
    unsigned* bucketed = (unsigned*)(p + off);  size_t bucketed_off = off; off += aln((size_t)NB * CAP * 4);
    int* bcursor = (int*)(p + off);             off += aln((size_t)(1024 + n) * 4);
    int* cntg = bcursor + 1024;                 // contiguous with bcursor for single zero pass
    bool fast_ok = (off <= ws_size) && (NB <= 1024);

    gemm_tile_k<<<(n + 63) / 64, 256, 0, stream>>>(x, W, h, n);

    if (fast_ok) {
        int ablocks = (E + ACH - 1) / ACH;
        zero_i32_k<<<(1024 + n + 255) / 256, 256, 0, stream>>>(bcursor, 1024 + n);
        passA_scatter_k<<<ablocks, 512, 0, stream>>>(ei, yei, e1, e2, bcursor, bucketed, cntg, NB);
        b1scale_k<<<(n * 4 + 255) / 256, 256, 0, stream>>>(cntg, (unsigned*)h, n);
        passB2_k<<<NB, 512, 0, stream>>>(bucketed, bcursor, cntg, h, b, out, n);
    } else {
        int* cnt = (int*)(p + bucketed_off);
        zero_i32_k<<<(n + 255) / 256, 256, 0, stream>>>(cnt, n);
        count_k<<<(E + 255) / 256, 256, 0, stream>>>(ei, yei, cnt, e1, e2);
        dinv_k<<<(n + 255) / 256, 256, 0, stream>>>(cnt, dinv, n);
        selfbias_k<<<(out_size + 255) / 256, 256, 0, stream>>>(dinv, h, b, out, out_size);
        scatter_atomic_k<<<((size_t)E * LATD + 255) / 256, 256, 0, stream>>>(ei, yei, dinv, h, out, e1, e2);
    }
}

// Round 5
// 193.885 us; speedup vs baseline: 1.3470x; 1.3470x over previous
//
#include <hip/hip_runtime.h>
#include <hip/hip_bf16.h>

// GCNConv encoder — R19: reordered pipeline, zero RMW passes.
//   zero:   bcursor[1024] only
//   passA:  multisplit scatter (NO per-edge global atomics — R18's 103us regression:
//           device-scope atomics to random addrs bypass per-XCD L2, +60MB writes),
//           wave-level shfl scan (3 barriers, was 18)
//   b1hist: per-bucket histogram from bucketed -> deg[n] (int). 8MB read, slim.
//   gemm:   runs AFTER b1hist; fuses h = (x@W)*rsqrt(deg+1) into epilogue (kills the
//           25.6MB h-RMW prescale pass entirely)
//   B2:     deg from global (512B) -> wave shfl-scan; bucket staged ONCE into registers
//           (static idx), scatter to sorted LDS; register-accumulating sweep (MLP-16,
//           no memory-ordered ops in gather loop — R15/R16 lesson), ds_add_f32 segment
//           flush into block-owned oacc[128][32]; fused (neigh+self)*dinv+bias store.
//
// ws: dinv[n] f32 (fallback only) | h[n*32] bf16 | bucketed[NB*CAP] u32 | bcursor[1024]+deg[n]

#define LATD 32
#define INCH 128
#define BSH 7
#define BW 128
#define CAP 4096
#define ACH 2048

__device__ __forceinline__ void lds_fadd(float* p, float v) {
    // generic pointer to __shared__ carries the 32-bit LDS byte offset in its low word
    unsigned off = (unsigned)(unsigned long long)p;
    asm volatile("ds_add_f32 %0, %1" :: "v"(off), "v"(v) : "memory");
}

__device__ __forceinline__ void load_edge(const int* __restrict__ ei, const int* __restrict__ yei,
                                          int e1, int e2, int e, int& src, int& dst) {
    if (e < e1) { src = ei[e]; dst = ei[e1 + e]; }
    else        { int t = e - e1; src = yei[t]; dst = yei[e2 + t]; }
}

// ---------------- GEMM: 64-row tile, bf16 x-staging, fused dinv scale ----------------
__global__ __launch_bounds__(256) void gemm_tile_k(const float* __restrict__ x,
                                                   const float* __restrict__ W,
                                                   __hip_bfloat16* __restrict__ h,
                                                   const int* __restrict__ deg, int n) {
    __shared__ __hip_bfloat16 xs[64][136];
    __shared__ float Wl[INCH][LATD];
    int tid = threadIdx.x;
    {
        const float4* Wv = (const float4*)W;
        float4* Wlv = (float4*)&Wl[0][0];
#pragma unroll 2
        for (int i = 0; i < 4; ++i) Wlv[tid + 256 * i] = Wv[tid + 256 * i];
    }
    int row0 = blockIdx.x * 64;
#pragma unroll 4
    for (int v = tid; v < 64 * 32; v += 256) {
        int r = v >> 5, kc = v & 31;
        int gr = row0 + r;
        float4 val = make_float4(0.f, 0.f, 0.f, 0.f);
        if (gr < n) val = ((const float4*)(x + (size_t)gr * INCH))[kc];
        __hip_bfloat16 t4[4] = { __float2bfloat16(val.x), __float2bfloat16(val.y),
                                 __float2bfloat16(val.z), __float2bfloat16(val.w) };
        *(ushort4*)&xs[r][kc * 4] = *(const ushort4*)t4;
    }
    __syncthreads();
    int c = tid & 7, rr = tid >> 3;
    int j0 = c * 4, r0 = rr * 2;
    float acc[2][4] = {};
#pragma unroll 2
    for (int kk = 0; kk < INCH; kk += 4) {
        float4 w0 = *(const float4*)&Wl[kk + 0][j0];
        float4 w1 = *(const float4*)&Wl[kk + 1][j0];
        float4 w2 = *(const float4*)&Wl[kk + 2][j0];
        float4 w3 = *(const float4*)&Wl[kk + 3][j0];
#pragma unroll
        for (int ri = 0; ri < 2; ++ri) {
            ushort4 u = *(const ushort4*)&xs[r0 + ri][kk];
            float a0 = __bfloat162float(*(const __hip_bfloat16*)&u.x);
            float a1 = __bfloat162float(*(const __hip_bfloat16*)&u.y);
            float a2 = __bfloat162float(*(const __hip_bfloat16*)&u.z);
            float a3 = __bfloat162float(*(const __hip_bfloat16*)&u.w);
            acc[ri][0] += a0 * w0.x + a1 * w1.x + a2 * w2.x + a3 * w3.x;
            acc[ri][1] += a0 * w0.y + a1 * w1.y + a2 * w2.y + a3 * w3.y;
            acc[ri][2] += a0 * w0.z + a1 * w1.z + a2 * w2.z + a3 * w3.z;
            acc[ri][3] += a0 * w0.w + a1 * w1.w + a2 * w2.w + a3 * w3.w;
        }
    }
#pragma unroll
    for (int ri = 0; ri < 2; ++ri) {
        int gr = row0 + r0 + ri;
        if (gr < n) {
            float dv = deg ? rsqrtf((float)deg[gr] + 1.0f) : 1.0f;
            __hip_bfloat16 tmp[4];
#pragma unroll
            for (int cj = 0; cj < 4; ++cj) tmp[cj] = __float2bfloat16(acc[ri][cj] * dv);
            *(ushort4*)(&h[(size_t)gr * LATD + j0]) = *(const ushort4*)tmp;
        }
    }
}

__global__ void zero_i32_k(int* p, int cnt) {
    int i = blockIdx.x * 256 + threadIdx.x;
    if (i < cnt) p[i] = 0;
}

// ---------------- pass A: multisplit scatter, wave-scan (no global atomics) ----------------
__global__ __launch_bounds__(512) void passA_scatter_k(const int* __restrict__ ei, const int* __restrict__ yei,
                                                       int e1, int e2, int* __restrict__ bcursor,
                                                       unsigned* __restrict__ bucketed, int NB) {
    __shared__ int hist[1024];
    __shared__ int scanex[1024];
    __shared__ int segb[1024];
    __shared__ int wsum[8], wbase[8];
    __shared__ unsigned raw[ACH];           // pk in arrival order
    __shared__ unsigned short rawb[ACH];    // bucket in arrival order
    __shared__ unsigned stage[ACH];         // pk sorted by bucket
    __shared__ unsigned short bof[ACH];     // bucket sorted
    int tid = threadIdx.x;
    int E = e1 + e2;
    int e0 = blockIdx.x * ACH;
    int m = E - e0; if (m > ACH) m = ACH;
    for (int i = tid; i < 1024; i += 512) hist[i] = 0;
    __syncthreads();
    for (int i = tid; i < m; i += 512) {
        int src, dst; load_edge(ei, yei, e1, e2, e0 + i, src, dst);
        int b = dst >> BSH;
        raw[i]  = ((unsigned)src << BSH) | (unsigned)(dst & (BW - 1));
        rawb[i] = (unsigned short)b;
        atomicAdd(&hist[b], 1);
    }
    __syncthreads();
    // exclusive scan of hist[1024]: 2 buckets/thread, per-wave shfl scan + wave combine
    int b2i = tid * 2;
    int c0 = hist[b2i], c1 = hist[b2i + 1];
    int pair = c0 + c1;
    int lane = tid & 63, wv = tid >> 6;
    int incl = pair;
#pragma unroll
    for (int off = 1; off < 64; off <<= 1) {
        int t = __shfl_up(incl, off);
        if (lane >= off) incl += t;
    }
    if (lane == 63) wsum[wv] = incl;
    __syncthreads();
    if (tid < 8) {
        int v = wsum[tid];
        int inc2 = v;
#pragma unroll
        for (int off = 1; off < 8; off <<= 1) {
            int t = __shfl_up(inc2, off);
            if (tid >= off) inc2 += t;
        }
        wbase[tid] = inc2 - v;   // exclusive wave base
    }
    __syncthreads();
    int excl = wbase[wv] + incl - pair;
    scanex[b2i] = excl; scanex[b2i + 1] = excl + c0;
    __syncthreads();
    for (int b = tid; b < NB; b += 512)
        segb[b] = hist[b] ? atomicAdd(&bcursor[b], hist[b]) : 0;
    __syncthreads();
    for (int b = tid; b < 1024; b += 512) hist[b] = scanex[b];   // repurpose as cursor
    __syncthreads();
    for (int i = tid; i < m; i += 512) {
        unsigned pk = raw[i]; int b = rawb[i];
        int pos = atomicAdd(&hist[b], 1);
        stage[pos] = pk;
        bof[pos] = (unsigned short)b;
    }
    __syncthreads();
    for (int i = tid; i < m; i += 512) {
        int b = bof[i];
        int pos = segb[b] + (i - scanex[b]);
        if (pos < CAP)
            bucketed[(size_t)b * CAP + pos] = stage[i];
    }
}

// ---------------- b1hist: per-bucket histogram -> deg[n] (int) ----------------
__global__ __launch_bounds__(512) void b1hist_k(const unsigned* __restrict__ bucketed,
                                                const int* __restrict__ bcursor,
                                                int* __restrict__ deg, int n) {
    __shared__ int cnt[BW];
    int tid = threadIdx.x;
    int b = blockIdx.x;
    size_t s = (size_t)b * CAP;
    int tot = bcursor[b]; if (tot > CAP) tot = CAP;
    int dst0 = b << BSH;
    if (tid < BW) cnt[tid] = 0;
    __syncthreads();
    for (int i = tid; i < tot; i += 512)
        atomicAdd(&cnt[bucketed[s + i] & (BW - 1)], 1);
    __syncthreads();
    if (tid < BW) {
        int node = dst0 + tid;
        if (node < n) deg[node] = cnt[tid];
    }
}

// ---------------- B2: reg-staged single-read sort; register sweep; fused store ----------------
__global__ __launch_bounds__(512) void passB2_k(const unsigned* __restrict__ bucketed,
                                                const int* __restrict__ bcursor,
                                                const int* __restrict__ deg,
                                                const __hip_bfloat16* __restrict__ hs,
                                                const float* __restrict__ bias,
                                                float* __restrict__ out, int n) {
    __shared__ unsigned sorted[CAP];     // 16 KB
    __shared__ float oacc[BW][LATD];     // 16 KB accumulator tile (this block owns dst rows)
    __shared__ int cnt[BW], cur[BW];
    int tid = threadIdx.x;
    int b = blockIdx.x;
    size_t s = (size_t)b * CAP;
    int tot = bcursor[b]; if (tot > CAP) tot = CAP;
    int dst0 = b << BSH;
    // register-stage the bucket (static indexing — dynamic idx would spill to scratch)
    unsigned ereg[8];
#pragma unroll
    for (int k = 0; k < 8; ++k) {
        int i = tid + (k << 9);
        ereg[k] = (i < tot) ? bucketed[s + i] : 0xFFFFFFFFu;   // pk < 2^24, sentinel safe
    }
    if (tid < BW) {
        int node = dst0 + tid;
        cnt[tid] = (node < n) ? deg[node] : 0;
    }
    for (int i = tid; i < BW * LATD; i += 512) ((float*)oacc)[i] = 0.f;
    __syncthreads();
    // wave-0 exclusive scan over 128 counts (2 per lane)
    if (tid < 64) {
        int b2 = tid * 2;
        int c0 = cnt[b2], c1 = cnt[b2 + 1];
        int pair = c0 + c1;
        int incl = pair;
#pragma unroll
        for (int off = 1; off < 64; off <<= 1) {
            int t = __shfl_up(incl, off);
            if (tid >= off) incl += t;
        }
        int excl = incl - pair;
        cur[b2] = excl; cur[b2 + 1] = excl + c0;
    }
    __syncthreads();
    // counting-sort scatter from registers into LDS
#pragma unroll
    for (int k = 0; k < 8; ++k) {
        unsigned e = ereg[k];
        if (e != 0xFFFFFFFFu) {
            int p = atomicAdd(&cur[e & (BW - 1)], 1);
            if (p < CAP) sorted[p] = e;
        }
    }
    __syncthreads();
    // segmented sweep: register accumulation, MLP-16 gather batches (NO memory-ordered
    // ops in the gather loop), rare ds_add_f32 flush per node-segment
    int g = tid >> 5, j = tid & 31;
    int span = (((tot + 15) >> 4) + 31) & ~31;
    int gs = g * span;
    int ge = gs + span; if (ge > tot) ge = tot;
    if (gs < tot) {
        float acc = 0.0f;
        int cur_ld = -1;
        for (int base = gs; base < ge; base += 32) {
            int mm = ge - base; if (mm > 32) mm = 32;
            if (mm == 32) {
#pragma unroll
                for (int ph = 0; ph < 2; ++ph) {
                    unsigned pk16[16]; float v16[16];
#pragma unroll
                    for (int t = 0; t < 16; ++t) {
                        pk16[t] = sorted[base + ph * 16 + t];              // LDS broadcast
                        v16[t] = __bfloat162float(hs[(size_t)(pk16[t] >> BSH) * LATD + j]);
                    }
#pragma unroll
                    for (int t = 0; t < 16; ++t) {
                        int ld = (int)(pk16[t] & (BW - 1));
                        if (ld != cur_ld) {
                            if (cur_ld >= 0) lds_fadd(&oacc[cur_ld][j], acc);
                            cur_ld = ld; acc = 0.0f;
                        }
                        acc += v16[t];
                    }
                }
            } else {
#pragma unroll 4
                for (int t = 0; t < mm; ++t) {
                    unsigned pk = sorted[base + t];
                    float v = __bfloat162float(hs[(size_t)(pk >> BSH) * LATD + j]);
                    int ld = (int)(pk & (BW - 1));
                    if (ld != cur_ld) {
                        if (cur_ld >= 0) lds_fadd(&oacc[cur_ld][j], acc);
                        cur_ld = ld; acc = 0.0f;
                    }
                    acc += v;
                }
            }
        }
        if (cur_ld >= 0) lds_fadd(&oacc[cur_ld][j], acc);
    }
    __syncthreads();   // waits lgkmcnt(0) -> all ds_add flushes visible
    // out = (neigh_acc + hs_self) * dinv + bias   (hs pre-scaled by gemm; dinv from cnt)
    for (int idx = tid; idx < BW * (LATD / 4); idx += 512) {
        int ld = idx >> 3, q = idx & 7;
        int node = dst0 + ld;
        if (node >= n) continue;
        float dv = rsqrtf((float)cnt[ld] + 1.0f);
        int j0 = q * 4;
        ushort4 u = *(const ushort4*)&hs[(size_t)node * LATD + j0];
        float4 bv = *(const float4*)&bias[j0];
        float4 o;
        o.x = (oacc[ld][j0 + 0] + __bfloat162float(*(const __hip_bfloat16*)&u.x)) * dv + bv.x;
        o.y = (oacc[ld][j0 + 1] + __bfloat162float(*(const __hip_bfloat16*)&u.y)) * dv + bv.y;
        o.z = (oacc[ld][j0 + 2] + __bfloat162float(*(const __hip_bfloat16*)&u.z)) * dv + bv.z;
        o.w = (oacc[ld][j0 + 3] + __bfloat162float(*(const __hip_bfloat16*)&u.w)) * dv + bv.w;
        *(float4*)&out[(size_t)node * LATD + j0] = o;
    }
}

// ---------------- fallback path (atomic scatter; uses UNSCALED h) ----------------
__global__ void count_k(const int* __restrict__ ei, const int* __restrict__ yei,
                        int* __restrict__ cnt, int e1, int e2) {
    int e = blockIdx.x * 256 + threadIdx.x;
    if (e >= e1 + e2) return;
    int src, dst; load_edge(ei, yei, e1, e2, e, src, dst);
    atomicAdd(&cnt[dst], 1);
}

__global__ void dinv_k(const int* __restrict__ cnt, float* __restrict__ dinv, int n) {
    int i = blockIdx.x * 256 + threadIdx.x;
    if (i < n) dinv[i] = rsqrtf((float)cnt[i] + 1.0f);
}

__global__ void selfbias_k(const float* __restrict__ dinv, const __hip_bfloat16* __restrict__ h,
                           const float* __restrict__ b, float* __restrict__ out, int total) {
    int idx = blockIdx.x * 256 + threadIdx.x;
    if (idx >= total) return;
    int i = idx >> 5, j = idx & 31;
    float d = dinv[i];
    out[idx] = __bfloat162float(h[idx]) * d * d + b[j];
}

__global__ void scatter_atomic_k(const int* __restrict__ ei, const int* __restrict__ yei,
                                 const float* __restrict__ dinv, const __hip_bfloat16* __restrict__ h,
                                 float* __restrict__ out, int e1, int e2) {
    int idx = blockIdx.x * 256 + threadIdx.x;
    int e = idx >> 5;
    if (e >= e1 + e2) return;
    int j = idx & 31;
    int src, dst; load_edge(ei, yei, e1, e2, e, src, dst);
    float norm = dinv[src] * dinv[dst];
    atomicAdd(&out[(size_t)dst * LATD + j], __bfloat162float(h[(size_t)src * LATD + j]) * norm);
}

static inline size_t aln(size_t x) { return (x + 255) & ~(size_t)255; }

extern "C" void kernel_launch(void* const* d_in, const int* in_sizes, int n_in,
                              void* d_out, int out_size, void* d_ws, size_t ws_size,
                              hipStream_t stream) {
    const float* x  = (const float*)d_in[0];
    const int* ei   = (const int*)d_in[1];
    const int* yei  = (const int*)d_in[2];
    const float* W  = (const float*)d_in[3];
    const float* b  = (const float*)d_in[4];
    float* out = (float*)d_out;

    int n  = in_sizes[0] / INCH;
    int e1 = in_sizes[1] / 2;
    int e2 = in_sizes[2] / 2;
    int E  = e1 + e2;
    int NB = (n + BW - 1) >> BSH;

    char* p = (char*)d_ws;
    size_t off = 0;
    float* dinv = (float*)(p + off);            off += aln((size_t)n * 4);
    __hip_bfloat16* h = (__hip_bfloat16*)(p + off); off += aln((size_t)n * LATD * 2);
    unsigned* bucketed = (unsigned*)(p + off);  size_t bucketed_off = off; off += aln((size_t)NB * CAP * 4);
    int* bcursor = (int*)(p + off);             off += aln((size_t)(1024 + n) * 4);
    int* deg = bcursor + 1024;
    bool fast_ok = (off <= ws_size) && (NB <= 1024);

    if (fast_ok) {
        int ablocks = (E + ACH - 1) / ACH;
        zero_i32_k<<<4, 256, 0, stream>>>(bcursor, 1024);
        passA_scatter_k<<<ablocks, 512, 0, stream>>>(ei, yei, e1, e2, bcursor, bucketed, NB);
        b1hist_k<<<NB, 512, 0, stream>>>(bucketed, bcursor, deg, n);
        gemm_tile_k<<<(n + 63) / 64, 256, 0, stream>>>(x, W, h, deg, n);   // fused *dinv
        passB2_k<<<NB, 512, 0, stream>>>(bucketed, bcursor, deg, h, b, out, n);
    } else {
        gemm_tile_k<<<(n + 63) / 64, 256, 0, stream>>>(x, W, h, nullptr, n); // unscaled
        int* cnt = (int*)(p + bucketed_off);
        zero_i32_k<<<(n + 255) / 256, 256, 0, stream>>>(cnt, n);
        count_k<<<(E + 255) / 256, 256, 0, stream>>>(ei, yei, cnt, e1, e2);
        dinv_k<<<(n + 255) / 256, 256, 0, stream>>>(cnt, dinv, n);
        selfbias_k<<<(out_size + 255) / 256, 256, 0, stream>>>(dinv, h, b, out, out_size);
        scatter_atomic_k<<<((size_t)E * LATD + 255) / 256, 256, 0, stream>>>(ei, yei, dinv, h, out, e1, e2);
    }
}

// Round 6
// 175.527 us; speedup vs baseline: 1.4879x; 1.1046x over previous
//
#include <hip/hip_runtime.h>
#include <hip/hip_bf16.h>

// GCNConv encoder — R20:
//   zero:   bcursor[1024] only
//   passA:  multisplit, ACH=4096 (halves contended bcursor atomics ~565k->300k and
//           per-edge barrier overhead; 60KB LDS, 2 blocks/CU)
//   gemmF:  FUSED b1hist+gemm: bucket b = rows [128b,128b+128); histograms own bucket
//           (cnt in LDS), writes deg[] for B2, scales h=(x@W)*rsqrt(deg+1) in epilogue
//   B2:     reg-staged single-read sort; sweep restructured 32 groups x 16 lanes with
//           uint (2-col) gathers -> 2x independent latency chains (cold-HBM gathers were
//           the limit: VALU 28%, HBM 18%, Occ 44%); ds_add_f32 flush; fused store.
// LESSONS: per-edge ordered LDS ops in gather loop = serial chain (R15/16, 433us);
//          per-edge random global atomics = +60MB writes (R18, 103us).
//
// ws: dinv[n] f32 (fallback only) | h[n*32] bf16 | bucketed[NB*CAP] u32 | bcursor[1024]+deg[n]

#define LATD 32
#define INCH 128
#define BSH 7
#define BW 128
#define CAP 4096
#define ACH 4096

__device__ __forceinline__ void lds_fadd(float* p, float v) {
    // generic pointer to __shared__ carries the 32-bit LDS byte offset in its low word
    unsigned off = (unsigned)(unsigned long long)p;
    asm volatile("ds_add_f32 %0, %1" :: "v"(off), "v"(v) : "memory");
}

__device__ __forceinline__ void load_edge(const int* __restrict__ ei, const int* __restrict__ yei,
                                          int e1, int e2, int e, int& src, int& dst) {
    if (e < e1) { src = ei[e]; dst = ei[e1 + e]; }
    else        { int t = e - e1; src = yei[t]; dst = yei[e2 + t]; }
}

// ---------------- gemmF: fused bucket-histogram + 128-row GEMM + dinv scale ----------------
__global__ __launch_bounds__(512) void gemm_fused_k(const float* __restrict__ x,
                                                    const float* __restrict__ W,
                                                    __hip_bfloat16* __restrict__ h,
                                                    const unsigned* __restrict__ bucketed,
                                                    const int* __restrict__ bcursor,
                                                    int* __restrict__ deg, int n) {
    __shared__ __hip_bfloat16 xs[128][136];   // 34.8 KB
    __shared__ float Wl[INCH][LATD];          // 16 KB
    __shared__ int cnt[BW];
    int tid = threadIdx.x;
    int b = blockIdx.x;
    int row0 = b << BSH;
    // phase 0: histogram this block's bucket -> cnt (degree of rows row0..row0+127)
    if (bucketed) {
        if (tid < BW) cnt[tid] = 0;
        __syncthreads();
        size_t s = (size_t)b * CAP;
        int tot = bcursor[b]; if (tot > CAP) tot = CAP;
        for (int i = tid; i < tot; i += 512)
            atomicAdd(&cnt[bucketed[s + i] & (BW - 1)], 1);
        __syncthreads();
        if (tid < BW) {
            int node = row0 + tid;
            if (node < n) deg[node] = cnt[tid];
        }
    }
    // phase 1: stage W and x-tile
    {
        const float4* Wv = (const float4*)W;
        float4* Wlv = (float4*)&Wl[0][0];
#pragma unroll
        for (int i = 0; i < 2; ++i) Wlv[tid + 512 * i] = Wv[tid + 512 * i];
    }
#pragma unroll 4
    for (int v = tid; v < 128 * 32; v += 512) {
        int r = v >> 5, kc = v & 31;
        int gr = row0 + r;
        float4 val = make_float4(0.f, 0.f, 0.f, 0.f);
        if (gr < n) val = ((const float4*)(x + (size_t)gr * INCH))[kc];
        __hip_bfloat16 t4[4] = { __float2bfloat16(val.x), __float2bfloat16(val.y),
                                 __float2bfloat16(val.z), __float2bfloat16(val.w) };
        *(ushort4*)&xs[r][kc * 4] = *(const ushort4*)t4;
    }
    __syncthreads();
    int c = tid & 7, rr = tid >> 3;            // rr in 0..63
    int j0 = c * 4, r0 = rr * 2;               // rows 0..127
    float acc[2][4] = {};
#pragma unroll 2
    for (int kk = 0; kk < INCH; kk += 4) {
        float4 w0 = *(const float4*)&Wl[kk + 0][j0];
        float4 w1 = *(const float4*)&Wl[kk + 1][j0];
        float4 w2 = *(const float4*)&Wl[kk + 2][j0];
        float4 w3 = *(const float4*)&Wl[kk + 3][j0];
#pragma unroll
        for (int ri = 0; ri < 2; ++ri) {
            ushort4 u = *(const ushort4*)&xs[r0 + ri][kk];
            float a0 = __bfloat162float(*(const __hip_bfloat16*)&u.x);
            float a1 = __bfloat162float(*(const __hip_bfloat16*)&u.y);
            float a2 = __bfloat162float(*(const __hip_bfloat16*)&u.z);
            float a3 = __bfloat162float(*(const __hip_bfloat16*)&u.w);
            acc[ri][0] += a0 * w0.x + a1 * w1.x + a2 * w2.x + a3 * w3.x;
            acc[ri][1] += a0 * w0.y + a1 * w1.y + a2 * w2.y + a3 * w3.y;
            acc[ri][2] += a0 * w0.z + a1 * w1.z + a2 * w2.z + a3 * w3.z;
            acc[ri][3] += a0 * w0.w + a1 * w1.w + a2 * w2.w + a3 * w3.w;
        }
    }
#pragma unroll
    for (int ri = 0; ri < 2; ++ri) {
        int rl = r0 + ri;
        int gr = row0 + rl;
        if (gr < n) {
            float dv = bucketed ? rsqrtf((float)cnt[rl] + 1.0f) : 1.0f;
            __hip_bfloat16 tmp[4];
#pragma unroll
            for (int cj = 0; cj < 4; ++cj) tmp[cj] = __float2bfloat16(acc[ri][cj] * dv);
            *(ushort4*)(&h[(size_t)gr * LATD + j0]) = *(const ushort4*)tmp;
        }
    }
}

__global__ void zero_i32_k(int* p, int cnt) {
    int i = blockIdx.x * 256 + threadIdx.x;
    if (i < cnt) p[i] = 0;
}

// ---------------- pass A: multisplit scatter, ACH=4096, wave-scan ----------------
__global__ __launch_bounds__(512) void passA_scatter_k(const int* __restrict__ ei, const int* __restrict__ yei,
                                                       int e1, int e2, int* __restrict__ bcursor,
                                                       unsigned* __restrict__ bucketed, int NB) {
    __shared__ int hist[1024];
    __shared__ int scanex[1024];
    __shared__ int segb[1024];
    __shared__ int wsum[8], wbase[8];
    __shared__ unsigned raw[ACH];           // pk in arrival order (16 KB)
    __shared__ unsigned short rawb[ACH];    // bucket in arrival order (8 KB)
    __shared__ unsigned stage[ACH];         // pk sorted by bucket (16 KB)
    __shared__ unsigned short bof[ACH];     // bucket sorted (8 KB)
    int tid = threadIdx.x;
    int E = e1 + e2;
    int e0 = blockIdx.x * ACH;
    int m = E - e0; if (m > ACH) m = ACH;
    for (int i = tid; i < 1024; i += 512) hist[i] = 0;
    __syncthreads();
    for (int i = tid; i < m; i += 512) {
        int src, dst; load_edge(ei, yei, e1, e2, e0 + i, src, dst);
        int b = dst >> BSH;
        raw[i]  = ((unsigned)src << BSH) | (unsigned)(dst & (BW - 1));
        rawb[i] = (unsigned short)b;
        atomicAdd(&hist[b], 1);
    }
    __syncthreads();
    // exclusive scan of hist[1024]: 2 buckets/thread, per-wave shfl scan + wave combine
    int b2i = tid * 2;
    int c0 = hist[b2i], c1 = hist[b2i + 1];
    int pair = c0 + c1;
    int lane = tid & 63, wv = tid >> 6;
    int incl = pair;
#pragma unroll
    for (int off = 1; off < 64; off <<= 1) {
        int t = __shfl_up(incl, off);
        if (lane >= off) incl += t;
    }
    if (lane == 63) wsum[wv] = incl;
    __syncthreads();
    if (tid < 8) {
        int v = wsum[tid];
        int inc2 = v;
#pragma unroll
        for (int off = 1; off < 8; off <<= 1) {
            int t = __shfl_up(inc2, off);
            if (tid >= off) inc2 += t;
        }
        wbase[tid] = inc2 - v;   // exclusive wave base
    }
    __syncthreads();
    int excl = wbase[wv] + incl - pair;
    scanex[b2i] = excl; scanex[b2i + 1] = excl + c0;
    __syncthreads();
    for (int b = tid; b < NB; b += 512)
        segb[b] = hist[b] ? atomicAdd(&bcursor[b], hist[b]) : 0;
    __syncthreads();
    for (int b = tid; b < 1024; b += 512) hist[b] = scanex[b];   // repurpose as cursor
    __syncthreads();
    for (int i = tid; i < m; i += 512) {
        unsigned pk = raw[i]; int b = rawb[i];
        int pos = atomicAdd(&hist[b], 1);
        stage[pos] = pk;
        bof[pos] = (unsigned short)b;
    }
    __syncthreads();
    for (int i = tid; i < m; i += 512) {
        int b = bof[i];
        int pos = segb[b] + (i - scanex[b]);
        if (pos < CAP)
            bucketed[(size_t)b * CAP + pos] = stage[i];
    }
}

// ---------------- B2: reg-staged sort; 32x16-group uint-gather sweep; fused store ----------------
__global__ __launch_bounds__(512) void passB2_k(const unsigned* __restrict__ bucketed,
                                                const int* __restrict__ bcursor,
                                                const int* __restrict__ deg,
                                                const __hip_bfloat16* __restrict__ hs,
                                                const float* __restrict__ bias,
                                                float* __restrict__ out, int n) {
    __shared__ unsigned sorted[CAP];     // 16 KB
    __shared__ float oacc[BW][LATD];     // 16 KB accumulator tile (this block owns dst rows)
    __shared__ int cnt[BW], cur[BW];
    int tid = threadIdx.x;
    int b = blockIdx.x;
    size_t s = (size_t)b * CAP;
    int tot = bcursor[b]; if (tot > CAP) tot = CAP;
    int dst0 = b << BSH;
    // register-stage the bucket (static indexing — dynamic idx would spill to scratch)
    unsigned ereg[8];
#pragma unroll
    for (int k = 0; k < 8; ++k) {
        int i = tid + (k << 9);
        ereg[k] = (i < tot) ? bucketed[s + i] : 0xFFFFFFFFu;   // pk < 2^24, sentinel safe
    }
    if (tid < BW) {
        int node = dst0 + tid;
        cnt[tid] = (node < n) ? deg[node] : 0;
    }
    for (int i = tid; i < BW * LATD; i += 512) ((float*)oacc)[i] = 0.f;
    __syncthreads();
    // wave-0 exclusive scan over 128 counts (2 per lane)
    if (tid < 64) {
        int b2 = tid * 2;
        int c0 = cnt[b2], c1 = cnt[b2 + 1];
        int pair = c0 + c1;
        int incl = pair;
#pragma unroll
        for (int off = 1; off < 64; off <<= 1) {
            int t = __shfl_up(incl, off);
            if (tid >= off) incl += t;
        }
        int excl = incl - pair;
        cur[b2] = excl; cur[b2 + 1] = excl + c0;
    }
    __syncthreads();
    // counting-sort scatter from registers into LDS
#pragma unroll
    for (int k = 0; k < 8; ++k) {
        unsigned e = ereg[k];
        if (e != 0xFFFFFFFFu) {
            int p = atomicAdd(&cur[e & (BW - 1)], 1);
            if (p < CAP) sorted[p] = e;
        }
    }
    __syncthreads();
    // segmented sweep: 32 groups x 16 lanes, each lane covers 2 columns via uint gather.
    // Register accumulation, MLP-16 batches (NO memory-ordered ops in the gather loop),
    // rare ds_add_f32 flush per node-segment.
    const unsigned* hs2 = (const unsigned*)hs;      // row stride = 16 uints
    int g = tid >> 4, j2 = tid & 15;
    int span = (((tot + 31) >> 5) + 15) & ~15;      // per-group span, multiple of 16
    int gs = g * span;
    int ge = gs + span; if (ge > tot) ge = tot;
    if (gs < tot) {
        float acc0 = 0.0f, acc1 = 0.0f;
        int cur_ld = -1;
        for (int base = gs; base < ge; base += 16) {
            int mm = ge - base; if (mm > 16) mm = 16;
            if (mm == 16) {
                unsigned pk16[16]; unsigned v16[16];
#pragma unroll
                for (int t = 0; t < 16; ++t) {
                    pk16[t] = sorted[base + t];                       // LDS broadcast
                    v16[t] = hs2[(size_t)(pk16[t] >> BSH) * 16 + j2];
                }
#pragma unroll
                for (int t = 0; t < 16; ++t) {
                    int ld = (int)(pk16[t] & (BW - 1));
                    if (ld != cur_ld) {
                        if (cur_ld >= 0) {
                            lds_fadd(&oacc[cur_ld][j2 * 2 + 0], acc0);
                            lds_fadd(&oacc[cur_ld][j2 * 2 + 1], acc1);
                        }
                        cur_ld = ld; acc0 = 0.0f; acc1 = 0.0f;
                    }
                    __hip_bfloat162 hv = *(__hip_bfloat162*)&v16[t];
                    float2 f = __bfloat1622float2(hv);
                    acc0 += f.x; acc1 += f.y;
                }
            } else {
#pragma unroll 4
                for (int t = 0; t < mm; ++t) {
                    unsigned pk = sorted[base + t];
                    unsigned v = hs2[(size_t)(pk >> BSH) * 16 + j2];
                    int ld = (int)(pk & (BW - 1));
                    if (ld != cur_ld) {
                        if (cur_ld >= 0) {
                            lds_fadd(&oacc[cur_ld][j2 * 2 + 0], acc0);
                            lds_fadd(&oacc[cur_ld][j2 * 2 + 1], acc1);
                        }
                        cur_ld = ld; acc0 = 0.0f; acc1 = 0.0f;
                    }
                    __hip_bfloat162 hv = *(__hip_bfloat162*)&v;
                    float2 f = __bfloat1622float2(hv);
                    acc0 += f.x; acc1 += f.y;
                }
            }
        }
        if (cur_ld >= 0) {
            lds_fadd(&oacc[cur_ld][j2 * 2 + 0], acc0);
            lds_fadd(&oacc[cur_ld][j2 * 2 + 1], acc1);
        }
    }
    __syncthreads();   // waits lgkmcnt(0) -> all ds_add flushes visible
    // out = (neigh_acc + hs_self) * dinv + bias   (hs pre-scaled by gemmF; dinv from cnt)
    for (int idx = tid; idx < BW * (LATD / 4); idx += 512) {
        int ld = idx >> 3, q = idx & 7;
        int node = dst0 + ld;
        if (node >= n) continue;
        float dv = rsqrtf((float)cnt[ld] + 1.0f);
        int j0 = q * 4;
        ushort4 u = *(const ushort4*)&hs[(size_t)node * LATD + j0];
        float4 bv = *(const float4*)&bias[j0];
        float4 o;
        o.x = (oacc[ld][j0 + 0] + __bfloat162float(*(const __hip_bfloat16*)&u.x)) * dv + bv.x;
        o.y = (oacc[ld][j0 + 1] + __bfloat162float(*(const __hip_bfloat16*)&u.y)) * dv + bv.y;
        o.z = (oacc[ld][j0 + 2] + __bfloat162float(*(const __hip_bfloat16*)&u.z)) * dv + bv.z;
        o.w = (oacc[ld][j0 + 3] + __bfloat162float(*(const __hip_bfloat16*)&u.w)) * dv + bv.w;
        *(float4*)&out[(size_t)node * LATD + j0] = o;
    }
}

// ---------------- fallback path (atomic scatter; uses UNSCALED h) ----------------
__global__ void count_k(const int* __restrict__ ei, const int* __restrict__ yei,
                        int* __restrict__ cnt, int e1, int e2) {
    int e = blockIdx.x * 256 + threadIdx.x;
    if (e >= e1 + e2) return;
    int src, dst; load_edge(ei, yei, e1, e2, e, src, dst);
    atomicAdd(&cnt[dst], 1);
}

__global__ void dinv_k(const int* __restrict__ cnt, float* __restrict__ dinv, int n) {
    int i = blockIdx.x * 256 + threadIdx.x;
    if (i < n) dinv[i] = rsqrtf((float)cnt[i] + 1.0f);
}

__global__ void selfbias_k(const float* __restrict__ dinv, const __hip_bfloat16* __restrict__ h,
                           const float* __restrict__ b, float* __restrict__ out, int total) {
    int idx = blockIdx.x * 256 + threadIdx.x;
    if (idx >= total) return;
    int i = idx >> 5, j = idx & 31;
    float d = dinv[i];
    out[idx] = __bfloat162float(h[idx]) * d * d + b[j];
}

__global__ void scatter_atomic_k(const int* __restrict__ ei, const int* __restrict__ yei,
                                 const float* __restrict__ dinv, const __hip_bfloat16* __restrict__ h,
                                 float* __restrict__ out, int e1, int e2) {
    int idx = blockIdx.x * 256 + threadIdx.x;
    int e = idx >> 5;
    if (e >= e1 + e2) return;
    int j = idx & 31;
    int src, dst; load_edge(ei, yei, e1, e2, e, src, dst);
    float norm = dinv[src] * dinv[dst];
    atomicAdd(&out[(size_t)dst * LATD + j], __bfloat162float(h[(size_t)src * LATD + j]) * norm);
}

static inline size_t aln(size_t x) { return (x + 255) & ~(size_t)255; }

extern "C" void kernel_launch(void* const* d_in, const int* in_sizes, int n_in,
                              void* d_out, int out_size, void* d_ws, size_t ws_size,
                              hipStream_t stream) {
    const float* x  = (const float*)d_in[0];
    const int* ei   = (const int*)d_in[1];
    const int* yei  = (const int*)d_in[2];
    const float* W  = (const float*)d_in[3];
    const float* b  = (const float*)d_in[4];
    float* out = (float*)d_out;

    int n  = in_sizes[0] / INCH;
    int e1 = in_sizes[1] / 2;
    int e2 = in_sizes[2] / 2;
    int E  = e1 + e2;
    int NB = (n + BW - 1) >> BSH;

    char* p = (char*)d_ws;
    size_t off = 0;
    float* dinv = (float*)(p + off);            off += aln((size_t)n * 4);
    __hip_bfloat16* h = (__hip_bfloat16*)(p + off); off += aln((size_t)n * LATD * 2);
    unsigned* bucketed = (unsigned*)(p + off);  size_t bucketed_off = off; off += aln((size_t)NB * CAP * 4);
    int* bcursor = (int*)(p + off);             off += aln((size_t)(1024 + n) * 4);
    int* deg = bcursor + 1024;
    bool fast_ok = (off <= ws_size) && (NB <= 1024);

    if (fast_ok) {
        int ablocks = (E + ACH - 1) / ACH;
        zero_i32_k<<<4, 256, 0, stream>>>(bcursor, 1024);
        passA_scatter_k<<<ablocks, 512, 0, stream>>>(ei, yei, e1, e2, bcursor, bucketed, NB);
        gemm_fused_k<<<NB, 512, 0, stream>>>(x, W, h, bucketed, bcursor, deg, n);  // hist+gemm+scale
        passB2_k<<<NB, 512, 0, stream>>>(bucketed, bcursor, deg, h, b, out, n);
    } else {
        gemm_fused_k<<<(n + 127) / 128, 512, 0, stream>>>(x, W, h, nullptr, nullptr, nullptr, n); // unscaled
        int* cnt = (int*)(p + bucketed_off);
        zero_i32_k<<<(n + 255) / 256, 256, 0, stream>>>(cnt, n);
        count_k<<<(E + 255) / 256, 256, 0, stream>>>(ei, yei, cnt, e1, e2);
        dinv_k<<<(n + 255) / 256, 256, 0, stream>>>(cnt, dinv, n);
        selfbias_k<<<(out_size + 255) / 256, 256, 0, stream>>>(dinv, h, b, out, out_size);
        scatter_atomic_k<<<((size_t)E * LATD + 255) / 256, 256, 0, stream>>>(ei, yei, dinv, h, out, e1, e2);
    }
}

// Round 8
// 166.635 us; speedup vs baseline: 1.5673x; 1.0534x over previous
//
#include <hip/hip_runtime.h>
#include <hip/hip_bf16.h>

// GCNConv encoder — R22 (R21 hardened; R21 bench failed, likely infra, but two risks
// removed: hipMemsetAsync in fallback (graph-capture tripwire) and __bf16 ext-vector
// operands (guide's compile-verified example uses short8 — now used here)).
//   prep:   zero bcursor + pre-swizzle W into MFMA B-fragment order (bf16, 8KB)
//   passA:  multisplit, ACH=4096 [unchanged from R20]
//   gemmF:  MFMA gemm (16x16x32 bf16, 8 waves x 16 rows, 2 col-tiles, K=128 in 4 steps)
//           + fused bucket-histogram (cnt in LDS -> deg[], *rsqrt(deg+1) epilogue).
//           No x/W LDS tiles — W fragments from L2, x rows straight to A-frags.
//           (R20 scalar gemm: 40.8us, VALU-bound on cvt+fma; MFMA kills that.)
//   B2:     reg-staged single-read sort; sweep 64 groups x 8 lanes, uint2 (4-col)
//           gathers -> 2x latency chains (grid-bound occupancy, can't add blocks);
//           ds_add_f32 flush; fused (neigh+self)*dinv+bias store.
// LESSONS: per-edge ordered LDS ops in gather loop = serial chain (R15/16, 433us);
//          per-edge random global atomics = +60MB writes (R18, 103us).
//
// Fragment layouts (learn_hip m89/m92-verified):
//   A: row = lane&15, k = 8*(lane>>4)+i (contiguous)   B: col = lane&15, same k-group
//   C/D: col = lane&15, row = 4*(lane>>4)+reg
//
// ws: dinv[n] f32 (fallback) | h[n*32] bf16 | bucketed[NB*CAP] u32 | bcursor[1024]+deg[n] | Wf[4096] bf16

#define LATD 32
#define INCH 128
#define BSH 7
#define BW 128
#define CAP 4096
#define ACH 4096

typedef short bf16x8 __attribute__((ext_vector_type(8)));   // 8 bf16 in 4 VGPRs (guide example)
typedef float f32x4 __attribute__((ext_vector_type(4)));

__device__ __forceinline__ short f2bf(float f) {
    __hip_bfloat16 t = __float2bfloat16(f);
    return *(short*)&t;
}

__device__ __forceinline__ void lds_fadd(float* p, float v) {
    // generic pointer to __shared__ carries the 32-bit LDS byte offset in its low word
    unsigned off = (unsigned)(unsigned long long)p;
    asm volatile("ds_add_f32 %0, %1" :: "v"(off), "v"(v) : "memory");
}

__device__ __forceinline__ void load_edge(const int* __restrict__ ei, const int* __restrict__ yei,
                                          int e1, int e2, int e, int& src, int& dst) {
    if (e < e1) { src = ei[e]; dst = ei[e1 + e]; }
    else        { int t = e - e1; src = yei[t]; dst = yei[e2 + t]; }
}

// ---------------- prep: zero bcursor + build W fragments ----------------
// Wf[((k>>3)*32 + c)*8 + (k&7)] = bf16(W[k][c])  => lane (c, k-group 4s+g) reads its
// 8-value k-run as one contiguous 16B bf16x8 at ((s*4+g)*32+c)*8.
__global__ void prep_k(const float* __restrict__ W, __hip_bfloat16* __restrict__ Wf,
                       int* __restrict__ bcursor) {
    int i = blockIdx.x * 256 + threadIdx.x;
    if (i < 1024) bcursor[i] = 0;
    int e = i - 1024;
    if (e >= 0 && e < INCH * LATD) {
        int k = e >> 5, c = e & 31;
        Wf[((k >> 3) * 32 + c) * 8 + (k & 7)] = __float2bfloat16(W[e]);
    }
}

// ---------------- gemmF: fused bucket-histogram + MFMA GEMM + dinv scale ----------------
__global__ __launch_bounds__(512) void gemm_fused_k(const float* __restrict__ x,
                                                    const __hip_bfloat16* __restrict__ Wf,
                                                    __hip_bfloat16* __restrict__ h,
                                                    const unsigned* __restrict__ bucketed,
                                                    const int* __restrict__ bcursor,
                                                    int* __restrict__ deg, int n) {
    __shared__ int cnt[BW];
    int tid = threadIdx.x;
    int b = blockIdx.x;
    int row0 = b << BSH;
    // phase 0: histogram this block's bucket -> cnt (degree of rows row0..row0+127)
    if (bucketed) {
        if (tid < BW) cnt[tid] = 0;
        __syncthreads();
        size_t s = (size_t)b * CAP;
        int tot = bcursor[b]; if (tot > CAP) tot = CAP;
        for (int i = tid; i < tot; i += 512)
            atomicAdd(&cnt[bucketed[s + i] & (BW - 1)], 1);
        __syncthreads();
        if (tid < BW) {
            int node = row0 + tid;
            if (node < n) deg[node] = cnt[tid];
        }
    }
    // phase 1: MFMA — wave wv owns rows row0+16*wv .. +15, cols 0..31 (2 tiles)
    int lane = tid & 63, wv = tid >> 6;
    int r = lane & 15, g = lane >> 4;         // A row / B col = r, k-group = g
    int grow = row0 + (wv << 4) + r;
    bool rok = grow < n;
    const float* xrow = x + (size_t)grow * INCH + g * 8;
    const short* Wfb = (const short*)Wf;
    f32x4 acc0 = {0.f, 0.f, 0.f, 0.f};
    f32x4 acc1 = {0.f, 0.f, 0.f, 0.f};
#pragma unroll
    for (int s = 0; s < 4; ++s) {             // K-step: k in [32s, 32s+32)
        bf16x8 af = {};
        if (rok) {
            float4 a0 = *(const float4*)(xrow + s * 32);
            float4 a1 = *(const float4*)(xrow + s * 32 + 4);
            af[0] = f2bf(a0.x); af[1] = f2bf(a0.y); af[2] = f2bf(a0.z); af[3] = f2bf(a0.w);
            af[4] = f2bf(a1.x); af[5] = f2bf(a1.y); af[6] = f2bf(a1.z); af[7] = f2bf(a1.w);
        }
        bf16x8 bf0 = *(const bf16x8*)(Wfb + (size_t)(((s * 4 + g) * 32) + r) * 8);
        bf16x8 bf1 = *(const bf16x8*)(Wfb + (size_t)(((s * 4 + g) * 32) + r + 16) * 8);
        acc0 = __builtin_amdgcn_mfma_f32_16x16x32_bf16(af, bf0, acc0, 0, 0, 0);
        acc1 = __builtin_amdgcn_mfma_f32_16x16x32_bf16(af, bf1, acc1, 0, 0, 0);
    }
    // epilogue: lane holds D[4g+i][r] (+16 cols for tile1); scale by rsqrt(deg+1), store bf16
#pragma unroll
    for (int i = 0; i < 4; ++i) {
        int rl = (wv << 4) + (g << 2) + i;
        int gr = row0 + rl;
        if (gr < n) {
            float dv = bucketed ? rsqrtf((float)cnt[rl] + 1.0f) : 1.0f;
            h[(size_t)gr * LATD + r]      = __float2bfloat16(acc0[i] * dv);
            h[(size_t)gr * LATD + r + 16] = __float2bfloat16(acc1[i] * dv);
        }
    }
}

__global__ void zero_i32_k(int* p, int cnt) {
    int i = blockIdx.x * 256 + threadIdx.x;
    if (i < cnt) p[i] = 0;
}

// ---------------- pass A: multisplit scatter, ACH=4096, wave-scan [unchanged] ----------------
__global__ __launch_bounds__(512) void passA_scatter_k(const int* __restrict__ ei, const int* __restrict__ yei,
                                                       int e1, int e2, int* __restrict__ bcursor,
                                                       unsigned* __restrict__ bucketed, int NB) {
    __shared__ int hist[1024];
    __shared__ int scanex[1024];
    __shared__ int segb[1024];
    __shared__ int wsum[8], wbase[8];
    __shared__ unsigned raw[ACH];           // pk in arrival order (16 KB)
    __shared__ unsigned short rawb[ACH];    // bucket in arrival order (8 KB)
    __shared__ unsigned stage[ACH];         // pk sorted by bucket (16 KB)
    __shared__ unsigned short bof[ACH];     // bucket sorted (8 KB)
    int tid = threadIdx.x;
    int E = e1 + e2;
    int e0 = blockIdx.x * ACH;
    int m = E - e0; if (m > ACH) m = ACH;
    for (int i = tid; i < 1024; i += 512) hist[i] = 0;
    __syncthreads();
    for (int i = tid; i < m; i += 512) {
        int src, dst; load_edge(ei, yei, e1, e2, e0 + i, src, dst);
        int b = dst >> BSH;
        raw[i]  = ((unsigned)src << BSH) | (unsigned)(dst & (BW - 1));
        rawb[i] = (unsigned short)b;
        atomicAdd(&hist[b], 1);
    }
    __syncthreads();
    // exclusive scan of hist[1024]: 2 buckets/thread, per-wave shfl scan + wave combine
    int b2i = tid * 2;
    int c0 = hist[b2i], c1 = hist[b2i + 1];
    int pair = c0 + c1;
    int lane = tid & 63, wv = tid >> 6;
    int incl = pair;
#pragma unroll
    for (int off = 1; off < 64; off <<= 1) {
        int t = __shfl_up(incl, off);
        if (lane >= off) incl += t;
    }
    if (lane == 63) wsum[wv] = incl;
    __syncthreads();
    if (tid < 8) {
        int v = wsum[tid];
        int inc2 = v;
#pragma unroll
        for (int off = 1; off < 8; off <<= 1) {
            int t = __shfl_up(inc2, off);
            if (tid >= off) inc2 += t;
        }
        wbase[tid] = inc2 - v;   // exclusive wave base
    }
    __syncthreads();
    int excl = wbase[wv] + incl - pair;
    scanex[b2i] = excl; scanex[b2i + 1] = excl + c0;
    __syncthreads();
    for (int b = tid; b < NB; b += 512)
        segb[b] = hist[b] ? atomicAdd(&bcursor[b], hist[b]) : 0;
    __syncthreads();
    for (int b = tid; b < 1024; b += 512) hist[b] = scanex[b];   // repurpose as cursor
    __syncthreads();
    for (int i = tid; i < m; i += 512) {
        unsigned pk = raw[i]; int b = rawb[i];
        int pos = atomicAdd(&hist[b], 1);
        stage[pos] = pk;
        bof[pos] = (unsigned short)b;
    }
    __syncthreads();
    for (int i = tid; i < m; i += 512) {
        int b = bof[i];
        int pos = segb[b] + (i - scanex[b]);
        if (pos < CAP)
            bucketed[(size_t)b * CAP + pos] = stage[i];
    }
}

// ---------------- B2: reg-staged sort; 64x8-group uint2-gather sweep; fused store ----------------
__global__ __launch_bounds__(512) void passB2_k(const unsigned* __restrict__ bucketed,
                                                const int* __restrict__ bcursor,
                                                const int* __restrict__ deg,
                                                const __hip_bfloat16* __restrict__ hs,
                                                const float* __restrict__ bias,
                                                float* __restrict__ out, int n) {
    __shared__ unsigned sorted[CAP];     // 16 KB
    __shared__ float oacc[BW][LATD];     // 16 KB accumulator tile (this block owns dst rows)
    __shared__ int cnt[BW], cur[BW];
    int tid = threadIdx.x;
    int b = blockIdx.x;
    size_t s = (size_t)b * CAP;
    int tot = bcursor[b]; if (tot > CAP) tot = CAP;
    int dst0 = b << BSH;
    // register-stage the bucket (static indexing — dynamic idx would spill to scratch)
    unsigned ereg[8];
#pragma unroll
    for (int k = 0; k < 8; ++k) {
        int i = tid + (k << 9);
        ereg[k] = (i < tot) ? bucketed[s + i] : 0xFFFFFFFFu;   // pk < 2^24, sentinel safe
    }
    if (tid < BW) {
        int node = dst0 + tid;
        cnt[tid] = (node < n) ? deg[node] : 0;
    }
    for (int i = tid; i < BW * LATD; i += 512) ((float*)oacc)[i] = 0.f;
    __syncthreads();
    // wave-0 exclusive scan over 128 counts (2 per lane)
    if (tid < 64) {
        int b2 = tid * 2;
        int c0 = cnt[b2], c1 = cnt[b2 + 1];
        int pair = c0 + c1;
        int incl = pair;
#pragma unroll
        for (int off = 1; off < 64; off <<= 1) {
            int t = __shfl_up(incl, off);
            if (tid >= off) incl += t;
        }
        int excl = incl - pair;
        cur[b2] = excl; cur[b2 + 1] = excl + c0;
    }
    __syncthreads();
    // counting-sort scatter from registers into LDS
#pragma unroll
    for (int k = 0; k < 8; ++k) {
        unsigned e = ereg[k];
        if (e != 0xFFFFFFFFu) {
            int p = atomicAdd(&cur[e & (BW - 1)], 1);
            if (p < CAP) sorted[p] = e;
        }
    }
    __syncthreads();
    // segmented sweep: 64 groups x 8 lanes, each lane covers 4 cols via uint2 gather.
    // Register accumulation, MLP-16 batches (NO memory-ordered ops in the gather loop),
    // rare ds_add_f32 flush per node-segment. 2x latency chains vs 32x16 (grid-bound).
    const uint2* hsv = (const uint2*)hs;            // row stride = 8 uint2
    int g = tid >> 3, j4 = tid & 7;
    int span = (((tot + 63) >> 6) + 15) & ~15;      // per-group span, multiple of 16
    int gs = g * span;
    int ge = gs + span; if (ge > tot) ge = tot;
    if (gs < tot) {
        float a0 = 0.f, a1 = 0.f, a2 = 0.f, a3 = 0.f;
        int cur_ld = -1;
        for (int base = gs; base < ge; base += 16) {
            int mm = ge - base; if (mm > 16) mm = 16;
            if (mm == 16) {
                unsigned pk16[16]; uint2 v16[16];
#pragma unroll
                for (int t = 0; t < 16; ++t) {
                    pk16[t] = sorted[base + t];                       // LDS broadcast
                    v16[t] = hsv[(size_t)(pk16[t] >> BSH) * 8 + j4];
                }
#pragma unroll
                for (int t = 0; t < 16; ++t) {
                    int ld = (int)(pk16[t] & (BW - 1));
                    if (ld != cur_ld) {
                        if (cur_ld >= 0) {
                            lds_fadd(&oacc[cur_ld][j4 * 4 + 0], a0);
                            lds_fadd(&oacc[cur_ld][j4 * 4 + 1], a1);
                            lds_fadd(&oacc[cur_ld][j4 * 4 + 2], a2);
                            lds_fadd(&oacc[cur_ld][j4 * 4 + 3], a3);
                        }
                        cur_ld = ld; a0 = a1 = a2 = a3 = 0.f;
                    }
                    __hip_bfloat162 p0 = *(__hip_bfloat162*)&v16[t].x;
                    __hip_bfloat162 p1 = *(__hip_bfloat162*)&v16[t].y;
                    float2 f0 = __bfloat1622float2(p0);
                    float2 f1 = __bfloat1622float2(p1);
                    a0 += f0.x; a1 += f0.y; a2 += f1.x; a3 += f1.y;
                }
            } else {
#pragma unroll 4
                for (int t = 0; t < mm; ++t) {
                    unsigned pk = sorted[base + t];
                    uint2 v = hsv[(size_t)(pk >> BSH) * 8 + j4];
                    int ld = (int)(pk & (BW - 1));
                    if (ld != cur_ld) {
                        if (cur_ld >= 0) {
                            lds_fadd(&oacc[cur_ld][j4 * 4 + 0], a0);
                            lds_fadd(&oacc[cur_ld][j4 * 4 + 1], a1);
                            lds_fadd(&oacc[cur_ld][j4 * 4 + 2], a2);
                            lds_fadd(&oacc[cur_ld][j4 * 4 + 3], a3);
                        }
                        cur_ld = ld; a0 = a1 = a2 = a3 = 0.f;
                    }
                    __hip_bfloat162 p0 = *(__hip_bfloat162*)&v.x;
                    __hip_bfloat162 p1 = *(__hip_bfloat162*)&v.y;
                    float2 f0 = __bfloat1622float2(p0);
                    float2 f1 = __bfloat1622float2(p1);
                    a0 += f0.x; a1 += f0.y; a2 += f1.x; a3 += f1.y;
                }
            }
        }
        if (cur_ld >= 0) {
            lds_fadd(&oacc[cur_ld][j4 * 4 + 0], a0);
            lds_fadd(&oacc[cur_ld][j4 * 4 + 1], a1);
            lds_fadd(&oacc[cur_ld][j4 * 4 + 2], a2);
            lds_fadd(&oacc[cur_ld][j4 * 4 + 3], a3);
        }
    }
    __syncthreads();   // waits lgkmcnt(0) -> all ds_add flushes visible
    // out = (neigh_acc + hs_self) * dinv + bias   (hs pre-scaled by gemmF; dinv from cnt)
    for (int idx = tid; idx < BW * (LATD / 4); idx += 512) {
        int ld = idx >> 3, q = idx & 7;
        int node = dst0 + ld;
        if (node >= n) continue;
        float dv = rsqrtf((float)cnt[ld] + 1.0f);
        int j0 = q * 4;
        ushort4 u = *(const ushort4*)&hs[(size_t)node * LATD + j0];
        float4 bv = *(const float4*)&bias[j0];
        float4 o;
        o.x = (oacc[ld][j0 + 0] + __bfloat162float(*(const __hip_bfloat16*)&u.x)) * dv + bv.x;
        o.y = (oacc[ld][j0 + 1] + __bfloat162float(*(const __hip_bfloat16*)&u.y)) * dv + bv.y;
        o.z = (oacc[ld][j0 + 2] + __bfloat162float(*(const __hip_bfloat16*)&u.z)) * dv + bv.z;
        o.w = (oacc[ld][j0 + 3] + __bfloat162float(*(const __hip_bfloat16*)&u.w)) * dv + bv.w;
        *(float4*)&out[(size_t)node * LATD + j0] = o;
    }
}

// ---------------- fallback path (atomic scatter; uses UNSCALED h) ----------------
__global__ void count_k(const int* __restrict__ ei, const int* __restrict__ yei,
                        int* __restrict__ cnt, int e1, int e2) {
    int e = blockIdx.x * 256 + threadIdx.x;
    if (e >= e1 + e2) return;
    int src, dst; load_edge(ei, yei, e1, e2, e, src, dst);
    atomicAdd(&cnt[dst], 1);
}

__global__ void dinv_k(const int* __restrict__ cnt, float* __restrict__ dinv, int n) {
    int i = blockIdx.x * 256 + threadIdx.x;
    if (i < n) dinv[i] = rsqrtf((float)cnt[i] + 1.0f);
}

__global__ void selfbias_k(const float* __restrict__ dinv, const __hip_bfloat16* __restrict__ h,
                           const float* __restrict__ b, float* __restrict__ out, int total) {
    int idx = blockIdx.x * 256 + threadIdx.x;
    if (idx >= total) return;
    int i = idx >> 5, j = idx & 31;
    float d = dinv[i];
    out[idx] = __bfloat162float(h[idx]) * d * d + b[j];
}

__global__ void scatter_atomic_k(const int* __restrict__ ei, const int* __restrict__ yei,
                                 const float* __restrict__ dinv, const __hip_bfloat16* __restrict__ h,
                                 float* __restrict__ out, int e1, int e2) {
    int idx = blockIdx.x * 256 + threadIdx.x;
    int e = idx >> 5;
    if (e >= e1 + e2) return;
    int j = idx & 31;
    int src, dst; load_edge(ei, yei, e1, e2, e, src, dst);
    float norm = dinv[src] * dinv[dst];
    atomicAdd(&out[(size_t)dst * LATD + j], __bfloat162float(h[(size_t)src * LATD + j]) * norm);
}

static inline size_t aln(size_t x) { return (x + 255) & ~(size_t)255; }

extern "C" void kernel_launch(void* const* d_in, const int* in_sizes, int n_in,
                              void* d_out, int out_size, void* d_ws, size_t ws_size,
                              hipStream_t stream) {
    const float* x  = (const float*)d_in[0];
    const int* ei   = (const int*)d_in[1];
    const int* yei  = (const int*)d_in[2];
    const float* W  = (const float*)d_in[3];
    const float* b  = (const float*)d_in[4];
    float* out = (float*)d_out;

    int n  = in_sizes[0] / INCH;
    int e1 = in_sizes[1] / 2;
    int e2 = in_sizes[2] / 2;
    int E  = e1 + e2;
    int NB = (n + BW - 1) >> BSH;

    char* p = (char*)d_ws;
    size_t off = 0;
    float* dinv = (float*)(p + off);            off += aln((size_t)n * 4);
    __hip_bfloat16* h = (__hip_bfloat16*)(p + off); off += aln((size_t)n * LATD * 2);
    unsigned* bucketed = (unsigned*)(p + off);  size_t bucketed_off = off; off += aln((size_t)NB * CAP * 4);
    int* bcursor = (int*)(p + off);             off += aln((size_t)(1024 + n) * 4);
    int* deg = bcursor + 1024;
    __hip_bfloat16* Wf = (__hip_bfloat16*)(p + off); off += aln((size_t)INCH * LATD * 2);
    bool fast_ok = (off <= ws_size) && (NB <= 1024);

    if (fast_ok) {
        int ablocks = (E + ACH - 1) / ACH;
        prep_k<<<20, 256, 0, stream>>>(W, Wf, bcursor);
        passA_scatter_k<<<ablocks, 512, 0, stream>>>(ei, yei, e1, e2, bcursor, bucketed, NB);
        gemm_fused_k<<<NB, 512, 0, stream>>>(x, Wf, h, bucketed, bcursor, deg, n);  // hist+MFMA+scale
        passB2_k<<<NB, 512, 0, stream>>>(bucketed, bcursor, deg, h, b, out, n);
    } else {
        prep_k<<<20, 256, 0, stream>>>(W, Wf, bcursor);
        gemm_fused_k<<<(n + 127) / 128, 512, 0, stream>>>(x, Wf, h, nullptr, nullptr, nullptr, n); // unscaled
        int* cntf = (int*)(p + bucketed_off);
        zero_i32_k<<<(n + 255) / 256, 256, 0, stream>>>(cntf, n);
        count_k<<<(E + 255) / 256, 256, 0, stream>>>(ei, yei, cntf, e1, e2);
        dinv_k<<<(n + 255) / 256, 256, 0, stream>>>(cntf, dinv, n);
        selfbias_k<<<(out_size + 255) / 256, 256, 0, stream>>>(dinv, h, b, out, out_size);
        scatter_atomic_k<<<((size_t)E * LATD + 255) / 256, 256, 0, stream>>>(ei, yei, dinv, h, out, e1, e2);
    }
}

// Round 9
// 154.524 us; speedup vs baseline: 1.6901x; 1.0784x over previous
//
#include <hip/hip_runtime.h>
#include <hip/hip_bf16.h>

// GCNConv encoder — R23:
//   prep:   zero bcursor + pre-swizzle W into MFMA B-fragment order (bf16, 8KB)
//   passA:  multisplit, ACH=4096 [unchanged]
//   gemmF:  MFMA gemm (16x16x32 bf16) + fused bucket-histogram + *rsqrt(deg+1) epilogue
//           [unchanged from R22 — verified working]
//   B2:     counting sort [unchanged], then PER-NODE sweep: each 8-lane group owns 2
//           nodes (edges contiguous after sort), BRANCHLESS batch-8 uint2 gathers,
//           register accumulation, one direct float4 out-write with self+bias+dinv
//           fused. Removes: divergent ld!=cur_ld flush (R22's cost — VALUBusy fell
//           while dur rose), oacc tile, all ds_add_f32, epilogue pass.
//           Batch=8 (not 16): R22's VGPR=36 proved compiler splits 16-deep batches;
//           8-deep keeps VGPR<=64 -> 8 waves/SIMD available.
// LESSONS: per-edge ordered LDS ops in gather loop = serial chain (R15/16, 433us);
//          per-edge random global atomics = +60MB writes (R18, 103us);
//          divergent per-edge branches in the sweep serialize the wave (R22).
//
// Fragment layouts (learn_hip m89/m92-verified):
//   A: row = lane&15, k = 8*(lane>>4)+i (contiguous)   B: col = lane&15, same k-group
//   C/D: col = lane&15, row = 4*(lane>>4)+reg
//
// ws: dinv[n] f32 (fallback) | h[n*32] bf16 | bucketed[NB*CAP] u32 | bcursor[1024]+deg[n] | Wf[4096] bf16

#define LATD 32
#define INCH 128
#define BSH 7
#define BW 128
#define CAP 4096
#define ACH 4096

typedef short bf16x8 __attribute__((ext_vector_type(8)));   // 8 bf16 in 4 VGPRs
typedef float f32x4 __attribute__((ext_vector_type(4)));

__device__ __forceinline__ short f2bf(float f) {
    __hip_bfloat16 t = __float2bfloat16(f);
    return *(short*)&t;
}

__device__ __forceinline__ void load_edge(const int* __restrict__ ei, const int* __restrict__ yei,
                                          int e1, int e2, int e, int& src, int& dst) {
    if (e < e1) { src = ei[e]; dst = ei[e1 + e]; }
    else        { int t = e - e1; src = yei[t]; dst = yei[e2 + t]; }
}

// ---------------- prep: zero bcursor + build W fragments ----------------
__global__ void prep_k(const float* __restrict__ W, __hip_bfloat16* __restrict__ Wf,
                       int* __restrict__ bcursor) {
    int i = blockIdx.x * 256 + threadIdx.x;
    if (i < 1024) bcursor[i] = 0;
    int e = i - 1024;
    if (e >= 0 && e < INCH * LATD) {
        int k = e >> 5, c = e & 31;
        Wf[((k >> 3) * 32 + c) * 8 + (k & 7)] = __float2bfloat16(W[e]);
    }
}

// ---------------- gemmF: fused bucket-histogram + MFMA GEMM + dinv scale ----------------
__global__ __launch_bounds__(512) void gemm_fused_k(const float* __restrict__ x,
                                                    const __hip_bfloat16* __restrict__ Wf,
                                                    __hip_bfloat16* __restrict__ h,
                                                    const unsigned* __restrict__ bucketed,
                                                    const int* __restrict__ bcursor,
                                                    int* __restrict__ deg, int n) {
    __shared__ int cnt[BW];
    int tid = threadIdx.x;
    int b = blockIdx.x;
    int row0 = b << BSH;
    if (bucketed) {
        if (tid < BW) cnt[tid] = 0;
        __syncthreads();
        size_t s = (size_t)b * CAP;
        int tot = bcursor[b]; if (tot > CAP) tot = CAP;
        for (int i = tid; i < tot; i += 512)
            atomicAdd(&cnt[bucketed[s + i] & (BW - 1)], 1);
        __syncthreads();
        if (tid < BW) {
            int node = row0 + tid;
            if (node < n) deg[node] = cnt[tid];
        }
    }
    int lane = tid & 63, wv = tid >> 6;
    int r = lane & 15, g = lane >> 4;
    int grow = row0 + (wv << 4) + r;
    bool rok = grow < n;
    const float* xrow = x + (size_t)grow * INCH + g * 8;
    const short* Wfb = (const short*)Wf;
    f32x4 acc0 = {0.f, 0.f, 0.f, 0.f};
    f32x4 acc1 = {0.f, 0.f, 0.f, 0.f};
#pragma unroll
    for (int s = 0; s < 4; ++s) {
        bf16x8 af = {};
        if (rok) {
            float4 a0 = *(const float4*)(xrow + s * 32);
            float4 a1 = *(const float4*)(xrow + s * 32 + 4);
            af[0] = f2bf(a0.x); af[1] = f2bf(a0.y); af[2] = f2bf(a0.z); af[3] = f2bf(a0.w);
            af[4] = f2bf(a1.x); af[5] = f2bf(a1.y); af[6] = f2bf(a1.z); af[7] = f2bf(a1.w);
        }
        bf16x8 bf0 = *(const bf16x8*)(Wfb + (size_t)(((s * 4 + g) * 32) + r) * 8);
        bf16x8 bf1 = *(const bf16x8*)(Wfb + (size_t)(((s * 4 + g) * 32) + r + 16) * 8);
        acc0 = __builtin_amdgcn_mfma_f32_16x16x32_bf16(af, bf0, acc0, 0, 0, 0);
        acc1 = __builtin_amdgcn_mfma_f32_16x16x32_bf16(af, bf1, acc1, 0, 0, 0);
    }
#pragma unroll
    for (int i = 0; i < 4; ++i) {
        int rl = (wv << 4) + (g << 2) + i;
        int gr = row0 + rl;
        if (gr < n) {
            float dv = bucketed ? rsqrtf((float)cnt[rl] + 1.0f) : 1.0f;
            h[(size_t)gr * LATD + r]      = __float2bfloat16(acc0[i] * dv);
            h[(size_t)gr * LATD + r + 16] = __float2bfloat16(acc1[i] * dv);
        }
    }
}

__global__ void zero_i32_k(int* p, int cnt) {
    int i = blockIdx.x * 256 + threadIdx.x;
    if (i < cnt) p[i] = 0;
}

// ---------------- pass A: multisplit scatter, ACH=4096, wave-scan [unchanged] ----------------
__global__ __launch_bounds__(512) void passA_scatter_k(const int* __restrict__ ei, const int* __restrict__ yei,
                                                       int e1, int e2, int* __restrict__ bcursor,
                                                       unsigned* __restrict__ bucketed, int NB) {
    __shared__ int hist[1024];
    __shared__ int scanex[1024];
    __shared__ int segb[1024];
    __shared__ int wsum[8], wbase[8];
    __shared__ unsigned raw[ACH];
    __shared__ unsigned short rawb[ACH];
    __shared__ unsigned stage[ACH];
    __shared__ unsigned short bof[ACH];
    int tid = threadIdx.x;
    int E = e1 + e2;
    int e0 = blockIdx.x * ACH;
    int m = E - e0; if (m > ACH) m = ACH;
    for (int i = tid; i < 1024; i += 512) hist[i] = 0;
    __syncthreads();
    for (int i = tid; i < m; i += 512) {
        int src, dst; load_edge(ei, yei, e1, e2, e0 + i, src, dst);
        int b = dst >> BSH;
        raw[i]  = ((unsigned)src << BSH) | (unsigned)(dst & (BW - 1));
        rawb[i] = (unsigned short)b;
        atomicAdd(&hist[b], 1);
    }
    __syncthreads();
    int b2i = tid * 2;
    int c0 = hist[b2i], c1 = hist[b2i + 1];
    int pair = c0 + c1;
    int lane = tid & 63, wv = tid >> 6;
    int incl = pair;
#pragma unroll
    for (int off = 1; off < 64; off <<= 1) {
        int t = __shfl_up(incl, off);
        if (lane >= off) incl += t;
    }
    if (lane == 63) wsum[wv] = incl;
    __syncthreads();
    if (tid < 8) {
        int v = wsum[tid];
        int inc2 = v;
#pragma unroll
        for (int off = 1; off < 8; off <<= 1) {
            int t = __shfl_up(inc2, off);
            if (tid >= off) inc2 += t;
        }
        wbase[tid] = inc2 - v;
    }
    __syncthreads();
    int excl = wbase[wv] + incl - pair;
    scanex[b2i] = excl; scanex[b2i + 1] = excl + c0;
    __syncthreads();
    for (int b = tid; b < NB; b += 512)
        segb[b] = hist[b] ? atomicAdd(&bcursor[b], hist[b]) : 0;
    __syncthreads();
    for (int b = tid; b < 1024; b += 512) hist[b] = scanex[b];
    __syncthreads();
    for (int i = tid; i < m; i += 512) {
        unsigned pk = raw[i]; int b = rawb[i];
        int pos = atomicAdd(&hist[b], 1);
        stage[pos] = pk;
        bof[pos] = (unsigned short)b;
    }
    __syncthreads();
    for (int i = tid; i < m; i += 512) {
        int b = bof[i];
        int pos = segb[b] + (i - scanex[b]);
        if (pos < CAP)
            bucketed[(size_t)b * CAP + pos] = stage[i];
    }
}

// ---------------- B2: sort + per-node branchless sweep; direct out writes ----------------
__global__ __launch_bounds__(512) void passB2_k(const unsigned* __restrict__ bucketed,
                                                const int* __restrict__ bcursor,
                                                const int* __restrict__ deg,
                                                const __hip_bfloat16* __restrict__ hs,
                                                const float* __restrict__ bias,
                                                float* __restrict__ out, int n) {
    __shared__ unsigned sorted[CAP];     // 16 KB
    __shared__ int cnt[BW], beg[BW], cur[BW];
    int tid = threadIdx.x;
    int b = blockIdx.x;
    size_t s = (size_t)b * CAP;
    int tot = bcursor[b]; if (tot > CAP) tot = CAP;
    int dst0 = b << BSH;
    // register-stage the bucket (static indexing)
    unsigned ereg[8];
#pragma unroll
    for (int k = 0; k < 8; ++k) {
        int i = tid + (k << 9);
        ereg[k] = (i < tot) ? bucketed[s + i] : 0xFFFFFFFFu;
    }
    if (tid < BW) {
        int node = dst0 + tid;
        cnt[tid] = (node < n) ? deg[node] : 0;
    }
    __syncthreads();
    // wave-0 exclusive scan over 128 counts (2 per lane); save segment starts in beg[]
    if (tid < 64) {
        int b2 = tid * 2;
        int c0 = cnt[b2], c1 = cnt[b2 + 1];
        int pair = c0 + c1;
        int incl = pair;
#pragma unroll
        for (int off = 1; off < 64; off <<= 1) {
            int t = __shfl_up(incl, off);
            if (tid >= off) incl += t;
        }
        int excl = incl - pair;
        beg[b2] = excl;      beg[b2 + 1] = excl + c0;
        cur[b2] = excl;      cur[b2 + 1] = excl + c0;
    }
    __syncthreads();
    // counting-sort scatter from registers into LDS
#pragma unroll
    for (int k = 0; k < 8; ++k) {
        unsigned e = ereg[k];
        if (e != 0xFFFFFFFFu) {
            int p = atomicAdd(&cur[e & (BW - 1)], 1);
            sorted[p] = e;
        }
    }
    __syncthreads();
    // per-node sweep: group g (8 lanes, j4 = 4 cols) owns nodes 2g, 2g+1.
    // Branchless batch-8 uint2 gathers, register accumulation, ONE float4 out-write
    // with self+bias+dinv fused. No per-edge branches, no LDS atomics, no oacc.
    const uint2* hsv = (const uint2*)hs;            // row stride = 8 uint2
    int g = tid >> 3, j4 = tid & 7;
#pragma unroll
    for (int q = 0; q < 2; ++q) {
        int nd = 2 * g + q;
        int node = dst0 + nd;
        int beg_ = beg[nd];
        int cnt_ = cnt[nd];
        float a0 = 0.f, a1 = 0.f, a2 = 0.f, a3 = 0.f;
        int i = 0;
        for (; i + 8 <= cnt_; i += 8) {
            unsigned pk8[8]; uint2 v8[8];
#pragma unroll
            for (int t = 0; t < 8; ++t) pk8[t] = sorted[beg_ + i + t];      // LDS broadcast
#pragma unroll
            for (int t = 0; t < 8; ++t) v8[t] = hsv[(size_t)(pk8[t] >> BSH) * 8 + j4];
#pragma unroll
            for (int t = 0; t < 8; ++t) {
                __hip_bfloat162 p0 = *(__hip_bfloat162*)&v8[t].x;
                __hip_bfloat162 p1 = *(__hip_bfloat162*)&v8[t].y;
                float2 f0 = __bfloat1622float2(p0);
                float2 f1 = __bfloat1622float2(p1);
                a0 += f0.x; a1 += f0.y; a2 += f1.x; a3 += f1.y;
            }
        }
#pragma unroll 4
        for (; i < cnt_; ++i) {
            unsigned pk = sorted[beg_ + i];
            uint2 v = hsv[(size_t)(pk >> BSH) * 8 + j4];
            __hip_bfloat162 p0 = *(__hip_bfloat162*)&v.x;
            __hip_bfloat162 p1 = *(__hip_bfloat162*)&v.y;
            float2 f0 = __bfloat1622float2(p0);
            float2 f1 = __bfloat1622float2(p1);
            a0 += f0.x; a1 += f0.y; a2 += f1.x; a3 += f1.y;
        }
        if (node < n) {
            float dv = rsqrtf((float)cnt_ + 1.0f);
            uint2 sv = hsv[(size_t)node * 8 + j4];                          // self (pre-scaled)
            __hip_bfloat162 s0 = *(__hip_bfloat162*)&sv.x;
            __hip_bfloat162 s1 = *(__hip_bfloat162*)&sv.y;
            float2 sf0 = __bfloat1622float2(s0);
            float2 sf1 = __bfloat1622float2(s1);
            float4 bv = *(const float4*)&bias[j4 * 4];
            float4 o;
            o.x = (a0 + sf0.x) * dv + bv.x;
            o.y = (a1 + sf0.y) * dv + bv.y;
            o.z = (a2 + sf1.x) * dv + bv.z;
            o.w = (a3 + sf1.y) * dv + bv.w;
            *(float4*)&out[(size_t)node * LATD + j4 * 4] = o;
        }
    }
}

// ---------------- fallback path (atomic scatter; uses UNSCALED h) ----------------
__global__ void count_k(const int* __restrict__ ei, const int* __restrict__ yei,
                        int* __restrict__ cnt, int e1, int e2) {
    int e = blockIdx.x * 256 + threadIdx.x;
    if (e >= e1 + e2) return;
    int src, dst; load_edge(ei, yei, e1, e2, e, src, dst);
    atomicAdd(&cnt[dst], 1);
}

__global__ void dinv_k(const int* __restrict__ cnt, float* __restrict__ dinv, int n) {
    int i = blockIdx.x * 256 + threadIdx.x;
    if (i < n) dinv[i] = rsqrtf((float)cnt[i] + 1.0f);
}

__global__ void selfbias_k(const float* __restrict__ dinv, const __hip_bfloat16* __restrict__ h,
                           const float* __restrict__ b, float* __restrict__ out, int total) {
    int idx = blockIdx.x * 256 + threadIdx.x;
    if (idx >= total) return;
    int i = idx >> 5, j = idx & 31;
    float d = dinv[i];
    out[idx] = __bfloat162float(h[idx]) * d * d + b[j];
}

__global__ void scatter_atomic_k(const int* __restrict__ ei, const int* __restrict__ yei,
                                 const float* __restrict__ dinv, const __hip_bfloat16* __restrict__ h,
                                 float* __restrict__ out, int e1, int e2) {
    int idx = blockIdx.x * 256 + threadIdx.x;
    int e = idx >> 5;
    if (e >= e1 + e2) return;
    int j = idx & 31;
    int src, dst; load_edge(ei, yei, e1, e2, e, src, dst);
    float norm = dinv[src] * dinv[dst];
    atomicAdd(&out[(size_t)dst * LATD + j], __bfloat162float(h[(size_t)src * LATD + j]) * norm);
}

static inline size_t aln(size_t x) { return (x + 255) & ~(size_t)255; }

extern "C" void kernel_launch(void* const* d_in, const int* in_sizes, int n_in,
                              void* d_out, int out_size, void* d_ws, size_t ws_size,
                              hipStream_t stream) {
    const float* x  = (const float*)d_in[0];
    const int* ei   = (const int*)d_in[1];
    const int* yei  = (const int*)d_in[2];
    const float* W  = (const float*)d_in[3];
    const float* b  = (const float*)d_in[4];
    float* out = (float*)d_out;

    int n  = in_sizes[0] / INCH;
    int e1 = in_sizes[1] / 2;
    int e2 = in_sizes[2] / 2;
    int E  = e1 + e2;
    int NB = (n + BW - 1) >> BSH;

    char* p = (char*)d_ws;
    size_t off = 0;
    float* dinv = (float*)(p + off);            off += aln((size_t)n * 4);
    __hip_bfloat16* h = (__hip_bfloat16*)(p + off); off += aln((size_t)n * LATD * 2);
    unsigned* bucketed = (unsigned*)(p + off);  size_t bucketed_off = off; off += aln((size_t)NB * CAP * 4);
    int* bcursor = (int*)(p + off);             off += aln((size_t)(1024 + n) * 4);
    int* deg = bcursor + 1024;
    __hip_bfloat16* Wf = (__hip_bfloat16*)(p + off); off += aln((size_t)INCH * LATD * 2);
    bool fast_ok = (off <= ws_size) && (NB <= 1024);

    if (fast_ok) {
        int ablocks = (E + ACH - 1) / ACH;
        prep_k<<<20, 256, 0, stream>>>(W, Wf, bcursor);
        passA_scatter_k<<<ablocks, 512, 0, stream>>>(ei, yei, e1, e2, bcursor, bucketed, NB);
        gemm_fused_k<<<NB, 512, 0, stream>>>(x, Wf, h, bucketed, bcursor, deg, n);  // hist+MFMA+scale
        passB2_k<<<NB, 512, 0, stream>>>(bucketed, bcursor, deg, h, b, out, n);
    } else {
        prep_k<<<20, 256, 0, stream>>>(W, Wf, bcursor);
        gemm_fused_k<<<(n + 127) / 128, 512, 0, stream>>>(x, Wf, h, nullptr, nullptr, nullptr, n); // unscaled
        int* cntf = (int*)(p + bucketed_off);
        zero_i32_k<<<(n + 255) / 256, 256, 0, stream>>>(cntf, n);
        count_k<<<(E + 255) / 256, 256, 0, stream>>>(ei, yei, cntf, e1, e2);
        dinv_k<<<(n + 255) / 256, 256, 0, stream>>>(cntf, dinv, n);
        selfbias_k<<<(out_size + 255) / 256, 256, 0, stream>>>(dinv, h, b, out, out_size);
        scatter_atomic_k<<<((size_t)E * LATD + 255) / 256, 256, 0, stream>>>(ei, yei, dinv, h, out, e1, e2);
    }
}

// Round 10
// 150.805 us; speedup vs baseline: 1.7318x; 1.0247x over previous
//
#include <hip/hip_runtime.h>
#include <hip/hip_bf16.h>

// GCNConv encoder — R24:
//   prep:   zero bcursor + pre-swizzle W into MFMA B-fragment order (bf16, 8KB)
//   passA:  multisplit, ACH=4096 [unchanged]
//   gemmF:  MFMA gemm + fused bucket-histogram + *rsqrt(deg+1) epilogue.
//           NEW: x A-fragment loads hoisted ABOVE the histogram phase (8 float4/thread
//           in flight across the 8.4MB hist scan — overlaps the 51.2MB x stream).
//   B2:     counting sort [unchanged]; sweep now 128 groups x 4 lanes, uint4 gathers,
//           exactly 1 node per group: same 64B/edge but HALF the load+unpack
//           instructions and 2x independent latency chains (B2 is latency-bound:
//           VALU 16-22%, HBM ~21%, grid-bound occupancy).
// LESSONS: per-edge ordered LDS ops in gather loop = serial chain (R15/16, 433us);
//          per-edge random global atomics = +60MB writes (R18, 103us);
//          divergent per-edge branches in the sweep serialize the wave (R22->R23 win).
//
// Fragment layouts (learn_hip m89/m92-verified):
//   A: row = lane&15, k = 8*(lane>>4)+i (contiguous)   B: col = lane&15, same k-group
//   C/D: col = lane&15, row = 4*(lane>>4)+reg
//
// ws: dinv[n] f32 (fallback) | h[n*32] bf16 | bucketed[NB*CAP] u32 | bcursor[1024]+deg[n] | Wf[4096] bf16

#define LATD 32
#define INCH 128
#define BSH 7
#define BW 128
#define CAP 4096
#define ACH 4096

typedef short bf16x8 __attribute__((ext_vector_type(8)));   // 8 bf16 in 4 VGPRs
typedef float f32x4 __attribute__((ext_vector_type(4)));

__device__ __forceinline__ short f2bf(float f) {
    __hip_bfloat16 t = __float2bfloat16(f);
    return *(short*)&t;
}

__device__ __forceinline__ void load_edge(const int* __restrict__ ei, const int* __restrict__ yei,
                                          int e1, int e2, int e, int& src, int& dst) {
    if (e < e1) { src = ei[e]; dst = ei[e1 + e]; }
    else        { int t = e - e1; src = yei[t]; dst = yei[e2 + t]; }
}

// ---------------- prep: zero bcursor + build W fragments ----------------
__global__ void prep_k(const float* __restrict__ W, __hip_bfloat16* __restrict__ Wf,
                       int* __restrict__ bcursor) {
    int i = blockIdx.x * 256 + threadIdx.x;
    if (i < 1024) bcursor[i] = 0;
    int e = i - 1024;
    if (e >= 0 && e < INCH * LATD) {
        int k = e >> 5, c = e & 31;
        Wf[((k >> 3) * 32 + c) * 8 + (k & 7)] = __float2bfloat16(W[e]);
    }
}

// ---------------- gemmF: fused bucket-histogram + MFMA GEMM + dinv scale ----------------
__global__ __launch_bounds__(512) void gemm_fused_k(const float* __restrict__ x,
                                                    const __hip_bfloat16* __restrict__ Wf,
                                                    __hip_bfloat16* __restrict__ h,
                                                    const unsigned* __restrict__ bucketed,
                                                    const int* __restrict__ bcursor,
                                                    int* __restrict__ deg, int n) {
    __shared__ int cnt[BW];
    int tid = threadIdx.x;
    int b = blockIdx.x;
    int row0 = b << BSH;
    // issue x loads FIRST — they ride out HBM latency under the histogram phase
    int lane = tid & 63, wv = tid >> 6;
    int r = lane & 15, g = lane >> 4;
    int grow = row0 + (wv << 4) + r;
    bool rok = grow < n;
    const float4* xrow4 = (const float4*)(x + (size_t)grow * INCH + g * 8);
    float4 xa[8];
#pragma unroll
    for (int s = 0; s < 4; ++s) {
        if (rok) {
            xa[2 * s]     = xrow4[s * 8];
            xa[2 * s + 1] = xrow4[s * 8 + 1];
        } else {
            xa[2 * s]     = make_float4(0.f, 0.f, 0.f, 0.f);
            xa[2 * s + 1] = make_float4(0.f, 0.f, 0.f, 0.f);
        }
    }
    // phase 0: histogram this block's bucket -> cnt (degree of rows row0..row0+127)
    if (bucketed) {
        if (tid < BW) cnt[tid] = 0;
        __syncthreads();
        size_t s = (size_t)b * CAP;
        int tot = bcursor[b]; if (tot > CAP) tot = CAP;
        for (int i = tid; i < tot; i += 512)
            atomicAdd(&cnt[bucketed[s + i] & (BW - 1)], 1);
        __syncthreads();
        if (tid < BW) {
            int node = row0 + tid;
            if (node < n) deg[node] = cnt[tid];
        }
    }
    // phase 1: MFMA — wave wv owns rows row0+16*wv .. +15, cols 0..31 (2 tiles)
    const short* Wfb = (const short*)Wf;
    f32x4 acc0 = {0.f, 0.f, 0.f, 0.f};
    f32x4 acc1 = {0.f, 0.f, 0.f, 0.f};
#pragma unroll
    for (int s = 0; s < 4; ++s) {
        float4 a0 = xa[2 * s], a1 = xa[2 * s + 1];
        bf16x8 af;
        af[0] = f2bf(a0.x); af[1] = f2bf(a0.y); af[2] = f2bf(a0.z); af[3] = f2bf(a0.w);
        af[4] = f2bf(a1.x); af[5] = f2bf(a1.y); af[6] = f2bf(a1.z); af[7] = f2bf(a1.w);
        bf16x8 bf0 = *(const bf16x8*)(Wfb + (size_t)(((s * 4 + g) * 32) + r) * 8);
        bf16x8 bf1 = *(const bf16x8*)(Wfb + (size_t)(((s * 4 + g) * 32) + r + 16) * 8);
        acc0 = __builtin_amdgcn_mfma_f32_16x16x32_bf16(af, bf0, acc0, 0, 0, 0);
        acc1 = __builtin_amdgcn_mfma_f32_16x16x32_bf16(af, bf1, acc1, 0, 0, 0);
    }
#pragma unroll
    for (int i = 0; i < 4; ++i) {
        int rl = (wv << 4) + (g << 2) + i;
        int gr = row0 + rl;
        if (gr < n) {
            float dv = bucketed ? rsqrtf((float)cnt[rl] + 1.0f) : 1.0f;
            h[(size_t)gr * LATD + r]      = __float2bfloat16(acc0[i] * dv);
            h[(size_t)gr * LATD + r + 16] = __float2bfloat16(acc1[i] * dv);
        }
    }
}

__global__ void zero_i32_k(int* p, int cnt) {
    int i = blockIdx.x * 256 + threadIdx.x;
    if (i < cnt) p[i] = 0;
}

// ---------------- pass A: multisplit scatter, ACH=4096, wave-scan [unchanged] ----------------
__global__ __launch_bounds__(512) void passA_scatter_k(const int* __restrict__ ei, const int* __restrict__ yei,
                                                       int e1, int e2, int* __restrict__ bcursor,
                                                       unsigned* __restrict__ bucketed, int NB) {
    __shared__ int hist[1024];
    __shared__ int scanex[1024];
    __shared__ int segb[1024];
    __shared__ int wsum[8], wbase[8];
    __shared__ unsigned raw[ACH];
    __shared__ unsigned short rawb[ACH];
    __shared__ unsigned stage[ACH];
    __shared__ unsigned short bof[ACH];
    int tid = threadIdx.x;
    int E = e1 + e2;
    int e0 = blockIdx.x * ACH;
    int m = E - e0; if (m > ACH) m = ACH;
    for (int i = tid; i < 1024; i += 512) hist[i] = 0;
    __syncthreads();
    for (int i = tid; i < m; i += 512) {
        int src, dst; load_edge(ei, yei, e1, e2, e0 + i, src, dst);
        int b = dst >> BSH;
        raw[i]  = ((unsigned)src << BSH) | (unsigned)(dst & (BW - 1));
        rawb[i] = (unsigned short)b;
        atomicAdd(&hist[b], 1);
    }
    __syncthreads();
    int b2i = tid * 2;
    int c0 = hist[b2i], c1 = hist[b2i + 1];
    int pair = c0 + c1;
    int lane = tid & 63, wv = tid >> 6;
    int incl = pair;
#pragma unroll
    for (int off = 1; off < 64; off <<= 1) {
        int t = __shfl_up(incl, off);
        if (lane >= off) incl += t;
    }
    if (lane == 63) wsum[wv] = incl;
    __syncthreads();
    if (tid < 8) {
        int v = wsum[tid];
        int inc2 = v;
#pragma unroll
        for (int off = 1; off < 8; off <<= 1) {
            int t = __shfl_up(inc2, off);
            if (tid >= off) inc2 += t;
        }
        wbase[tid] = inc2 - v;
    }
    __syncthreads();
    int excl = wbase[wv] + incl - pair;
    scanex[b2i] = excl; scanex[b2i + 1] = excl + c0;
    __syncthreads();
    for (int b = tid; b < NB; b += 512)
        segb[b] = hist[b] ? atomicAdd(&bcursor[b], hist[b]) : 0;
    __syncthreads();
    for (int b = tid; b < 1024; b += 512) hist[b] = scanex[b];
    __syncthreads();
    for (int i = tid; i < m; i += 512) {
        unsigned pk = raw[i]; int b = rawb[i];
        int pos = atomicAdd(&hist[b], 1);
        stage[pos] = pk;
        bof[pos] = (unsigned short)b;
    }
    __syncthreads();
    for (int i = tid; i < m; i += 512) {
        int b = bof[i];
        int pos = segb[b] + (i - scanex[b]);
        if (pos < CAP)
            bucketed[(size_t)b * CAP + pos] = stage[i];
    }
}

// ---------------- B2: sort + per-node 4-lane uint4 sweep; direct out writes ----------------
__global__ __launch_bounds__(512) void passB2_k(const unsigned* __restrict__ bucketed,
                                                const int* __restrict__ bcursor,
                                                const int* __restrict__ deg,
                                                const __hip_bfloat16* __restrict__ hs,
                                                const float* __restrict__ bias,
                                                float* __restrict__ out, int n) {
    __shared__ unsigned sorted[CAP];     // 16 KB
    __shared__ int cnt[BW], beg[BW], cur[BW];
    int tid = threadIdx.x;
    int b = blockIdx.x;
    size_t s = (size_t)b * CAP;
    int tot = bcursor[b]; if (tot > CAP) tot = CAP;
    int dst0 = b << BSH;
    // register-stage the bucket (static indexing)
    unsigned ereg[8];
#pragma unroll
    for (int k = 0; k < 8; ++k) {
        int i = tid + (k << 9);
        ereg[k] = (i < tot) ? bucketed[s + i] : 0xFFFFFFFFu;
    }
    if (tid < BW) {
        int node = dst0 + tid;
        cnt[tid] = (node < n) ? deg[node] : 0;
    }
    __syncthreads();
    // wave-0 exclusive scan over 128 counts (2 per lane); save segment starts in beg[]
    if (tid < 64) {
        int b2 = tid * 2;
        int c0 = cnt[b2], c1 = cnt[b2 + 1];
        int pair = c0 + c1;
        int incl = pair;
#pragma unroll
        for (int off = 1; off < 64; off <<= 1) {
            int t = __shfl_up(incl, off);
            if (tid >= off) incl += t;
        }
        int excl = incl - pair;
        beg[b2] = excl;      beg[b2 + 1] = excl + c0;
        cur[b2] = excl;      cur[b2 + 1] = excl + c0;
    }
    __syncthreads();
    // counting-sort scatter from registers into LDS
#pragma unroll
    for (int k = 0; k < 8; ++k) {
        unsigned e = ereg[k];
        if (e != 0xFFFFFFFFu) {
            int p = atomicAdd(&cur[e & (BW - 1)], 1);
            sorted[p] = e;
        }
    }
    __syncthreads();
    // per-node sweep: group g (4 lanes, j = 8-col slice) owns node g (128 groups).
    // Branchless batch-8 uint4 gathers, register accumulation, direct out-writes with
    // self+bias+dinv fused. Half the load/unpack instructions of the 8-lane variant,
    // 2x independent latency chains per wave.
    const uint4* hsv = (const uint4*)hs;            // row stride = 4 uint4
    int g = tid >> 2, j = tid & 3;
    int node = dst0 + g;
    int beg_ = beg[g];
    int cnt_ = cnt[g];
    float a0 = 0.f, a1 = 0.f, a2 = 0.f, a3 = 0.f;
    float a4 = 0.f, a5 = 0.f, a6 = 0.f, a7 = 0.f;
    int i = 0;
    for (; i + 8 <= cnt_; i += 8) {
        unsigned pk8[8]; uint4 v8[8];
#pragma unroll
        for (int t = 0; t < 8; ++t) pk8[t] = sorted[beg_ + i + t];        // LDS broadcast
#pragma unroll
        for (int t = 0; t < 8; ++t) v8[t] = hsv[(size_t)(pk8[t] >> BSH) * 4 + j];
#pragma unroll
        for (int t = 0; t < 8; ++t) {
            float2 f0 = __bfloat1622float2(*(__hip_bfloat162*)&v8[t].x);
            float2 f1 = __bfloat1622float2(*(__hip_bfloat162*)&v8[t].y);
            float2 f2 = __bfloat1622float2(*(__hip_bfloat162*)&v8[t].z);
            float2 f3 = __bfloat1622float2(*(__hip_bfloat162*)&v8[t].w);
            a0 += f0.x; a1 += f0.y; a2 += f1.x; a3 += f1.y;
            a4 += f2.x; a5 += f2.y; a6 += f3.x; a7 += f3.y;
        }
    }
#pragma unroll 4
    for (; i < cnt_; ++i) {
        unsigned pk = sorted[beg_ + i];
        uint4 v = hsv[(size_t)(pk >> BSH) * 4 + j];
        float2 f0 = __bfloat1622float2(*(__hip_bfloat162*)&v.x);
        float2 f1 = __bfloat1622float2(*(__hip_bfloat162*)&v.y);
        float2 f2 = __bfloat1622float2(*(__hip_bfloat162*)&v.z);
        float2 f3 = __bfloat1622float2(*(__hip_bfloat162*)&v.w);
        a0 += f0.x; a1 += f0.y; a2 += f1.x; a3 += f1.y;
        a4 += f2.x; a5 += f2.y; a6 += f3.x; a7 += f3.y;
    }
    if (node < n) {
        float dv = rsqrtf((float)cnt_ + 1.0f);
        uint4 sv = hsv[(size_t)node * 4 + j];                             // self (pre-scaled)
        float2 s0 = __bfloat1622float2(*(__hip_bfloat162*)&sv.x);
        float2 s1 = __bfloat1622float2(*(__hip_bfloat162*)&sv.y);
        float2 s2 = __bfloat1622float2(*(__hip_bfloat162*)&sv.z);
        float2 s3 = __bfloat1622float2(*(__hip_bfloat162*)&sv.w);
        float4 bv0 = *(const float4*)&bias[j * 8];
        float4 bv1 = *(const float4*)&bias[j * 8 + 4];
        float4 o0, o1;
        o0.x = (a0 + s0.x) * dv + bv0.x;
        o0.y = (a1 + s0.y) * dv + bv0.y;
        o0.z = (a2 + s1.x) * dv + bv0.z;
        o0.w = (a3 + s1.y) * dv + bv0.w;
        o1.x = (a4 + s2.x) * dv + bv1.x;
        o1.y = (a5 + s2.y) * dv + bv1.y;
        o1.z = (a6 + s3.x) * dv + bv1.z;
        o1.w = (a7 + s3.y) * dv + bv1.w;
        *(float4*)&out[(size_t)node * LATD + j * 8]     = o0;
        *(float4*)&out[(size_t)node * LATD + j * 8 + 4] = o1;
    }
}

// ---------------- fallback path (atomic scatter; uses UNSCALED h) ----------------
__global__ void count_k(const int* __restrict__ ei, const int* __restrict__ yei,
                        int* __restrict__ cnt, int e1, int e2) {
    int e = blockIdx.x * 256 + threadIdx.x;
    if (e >= e1 + e2) return;
    int src, dst; load_edge(ei, yei, e1, e2, e, src, dst);
    atomicAdd(&cnt[dst], 1);
}

__global__ void dinv_k(const int* __restrict__ cnt, float* __restrict__ dinv, int n) {
    int i = blockIdx.x * 256 + threadIdx.x;
    if (i < n) dinv[i] = rsqrtf((float)cnt[i] + 1.0f);
}

__global__ void selfbias_k(const float* __restrict__ dinv, const __hip_bfloat16* __restrict__ h,
                           const float* __restrict__ b, float* __restrict__ out, int total) {
    int idx = blockIdx.x * 256 + threadIdx.x;
    if (idx >= total) return;
    int i = idx >> 5, j = idx & 31;
    float d = dinv[i];
    out[idx] = __bfloat162float(h[idx]) * d * d + b[j];
}

__global__ void scatter_atomic_k(const int* __restrict__ ei, const int* __restrict__ yei,
                                 const float* __restrict__ dinv, const __hip_bfloat16* __restrict__ h,
                                 float* __restrict__ out, int e1, int e2) {
    int idx = blockIdx.x * 256 + threadIdx.x;
    int e = idx >> 5;
    if (e >= e1 + e2) return;
    int j = idx & 31;
    int src, dst; load_edge(ei, yei, e1, e2, e, src, dst);
    float norm = dinv[src] * dinv[dst];
    atomicAdd(&out[(size_t)dst * LATD + j], __bfloat162float(h[(size_t)src * LATD + j]) * norm);
}

static inline size_t aln(size_t x) { return (x + 255) & ~(size_t)255; }

extern "C" void kernel_launch(void* const* d_in, const int* in_sizes, int n_in,
                              void* d_out, int out_size, void* d_ws, size_t ws_size,
                              hipStream_t stream) {
    const float* x  = (const float*)d_in[0];
    const int* ei   = (const int*)d_in[1];
    const int* yei  = (const int*)d_in[2];
    const float* W  = (const float*)d_in[3];
    const float* b  = (const float*)d_in[4];
    float* out = (float*)d_out;

    int n  = in_sizes[0] / INCH;
    int e1 = in_sizes[1] / 2;
    int e2 = in_sizes[2] / 2;
    int E  = e1 + e2;
    int NB = (n + BW - 1) >> BSH;

    char* p = (char*)d_ws;
    size_t off = 0;
    float* dinv = (float*)(p + off);            off += aln((size_t)n * 4);
    __hip_bfloat16* h = (__hip_bfloat16*)(p + off); off += aln((size_t)n * LATD * 2);
    unsigned* bucketed = (unsigned*)(p + off);  size_t bucketed_off = off; off += aln((size_t)NB * CAP * 4);
    int* bcursor = (int*)(p + off);             off += aln((size_t)(1024 + n) * 4);
    int* deg = bcursor + 1024;
    __hip_bfloat16* Wf = (__hip_bfloat16*)(p + off); off += aln((size_t)INCH * LATD * 2);
    bool fast_ok = (off <= ws_size) && (NB <= 1024);

    if (fast_ok) {
        int ablocks = (E + ACH - 1) / ACH;
        prep_k<<<20, 256, 0, stream>>>(W, Wf, bcursor);
        passA_scatter_k<<<ablocks, 512, 0, stream>>>(ei, yei, e1, e2, bcursor, bucketed, NB);
        gemm_fused_k<<<NB, 512, 0, stream>>>(x, Wf, h, bucketed, bcursor, deg, n);  // hist+MFMA+scale
        passB2_k<<<NB, 512, 0, stream>>>(bucketed, bcursor, deg, h, b, out, n);
    } else {
        prep_k<<<20, 256, 0, stream>>>(W, Wf, bcursor);
        gemm_fused_k<<<(n + 127) / 128, 512, 0, stream>>>(x, Wf, h, nullptr, nullptr, nullptr, n); // unscaled
        int* cntf = (int*)(p + bucketed_off);
        zero_i32_k<<<(n + 255) / 256, 256, 0, stream>>>(cntf, n);
        count_k<<<(E + 255) / 256, 256, 0, stream>>>(ei, yei, cntf, e1, e2);
        dinv_k<<<(n + 255) / 256, 256, 0, stream>>>(cntf, dinv, n);
        selfbias_k<<<(out_size + 255) / 256, 256, 0, stream>>>(dinv, h, b, out, out_size);
        scatter_atomic_k<<<((size_t)E * LATD + 255) / 256, 256, 0, stream>>>(ei, yei, dinv, h, out, e1, e2);
    }
}